// Round 9
// baseline (1463.590 us; speedup 1.0000x reference)
//
#include <hip/hip_runtime.h>
#include <math.h>

#define NN  50000
#define NE  400000
#define NTE 50000
#define FIN 64
#define EDIM 32
#define HD  128
#define NL  2
#define SCAN_B ((NN + 255) / 256)

typedef __attribute__((ext_vector_type(8))) short bf16x8;
typedef __attribute__((ext_vector_type(4))) short bf16x4;
typedef __attribute__((ext_vector_type(4))) float f32x4;

static __device__ __forceinline__ unsigned short f2bf(float f) {
    unsigned u = __float_as_uint(f);
    unsigned r = (u + 0x7fffu + ((u >> 16) & 1u)) >> 16;
    return (unsigned short)r;
}
static __device__ __forceinline__ float bfhi2f(unsigned u) { return __uint_as_float(u & 0xffff0000u); }
static __device__ __forceinline__ float bflo2f(unsigned u) { return __uint_as_float(u << 16); }

static __device__ __forceinline__ bf16x8 load_a8(const float* p, bool ok) {
    bf16x8 a = {};
    if (ok) {
        const float4 v0 = *(const float4*)(p);
        const float4 v1 = *(const float4*)(p + 4);
        a[0] = (short)f2bf(v0.x); a[1] = (short)f2bf(v0.y);
        a[2] = (short)f2bf(v0.z); a[3] = (short)f2bf(v0.w);
        a[4] = (short)f2bf(v1.x); a[5] = (short)f2bf(v1.y);
        a[6] = (short)f2bf(v1.z); a[7] = (short)f2bf(v1.w);
    }
    return a;
}
static __device__ __forceinline__ bf16x4 pack4(float4 a) {
    bf16x4 v;
    v[0]=(short)f2bf(a.x); v[1]=(short)f2bf(a.y); v[2]=(short)f2bf(a.z); v[3]=(short)f2bf(a.w);
    return v;
}

// ---- pack fp32 W[K][128] into bf16 MFMA frag order: [(kb*8+nt)*64+lane][8] k-contig ----
__global__ void __launch_bounds__(256) k_packW(const float* __restrict__ W,
        unsigned short* __restrict__ out, int K)
{
    const int tid = blockIdx.x * 256 + threadIdx.x;
    const int total = (K / 32) * 512;
    if (tid >= total) return;
    const int lane = tid & 63, nt = (tid >> 6) & 7, kb = tid >> 9;
    const int k0 = kb * 32 + (lane >> 4) * 8;
    const int col = nt * 16 + (lane & 15);
    bf16x8 v;
    #pragma unroll
    for (int j = 0; j < 8; ++j)
        v[j] = (short)f2bf(W[(size_t)(k0 + j) * HD + col]);
    *(bf16x8*)(out + (size_t)tid * 8) = v;
}

// ---- fold layer-0 message weight: Wf = edgeW@We0 [32][128], bf = edgeb@We0 [128] ----
__global__ void __launch_bounds__(256) k_foldW(const float* __restrict__ edgeW,
        const float* __restrict__ edgeb, const float* __restrict__ We0,
        float* __restrict__ Wf, float* __restrict__ bf)
{
    const int tid = blockIdx.x * 256 + threadIdx.x;
    if (tid < 4096) {
        const int k = tid >> 7, c = tid & 127;
        float s = 0.f;
        for (int j = 0; j < 128; ++j) s += edgeW[k * HD + j] * We0[(size_t)j * HD + c];
        Wf[tid] = s;
    } else if (tid < 4224) {
        const int c = tid - 4096;
        float s = 0.f;
        for (int j = 0; j < 128; ++j) s += edgeb[j] * We0[(size_t)j * HD + c];
        bf[c] = s;
    }
}

// ---- transposed MFMA GEMM: C = A@W (+bias); lane owns one row, float4 stores ----
template<int KB>
__global__ void __launch_bounds__(256) k_gemm_T(const float* A,
        const unsigned short* __restrict__ Wpk, const float* __restrict__ bias,
        float* C, int M)
{
    const int t = threadIdx.x, w = t >> 6, l = t & 63;
    const int n = blockIdx.x * 64 + w * 16 + (l & 15);
    const bool ok = n < M;
    const int q = l >> 4;
    const int K = KB * 32;
    f32x4 acc[8] = {};
    #pragma unroll
    for (int kb = 0; kb < KB; ++kb) {
        const bf16x8 b = load_a8(A + (size_t)n * K + kb * 32 + q * 8, ok);
        #pragma unroll
        for (int nt = 0; nt < 8; ++nt) {
            const bf16x8 aW = *(const bf16x8*)(Wpk + (((size_t)(kb * 8 + nt) * 64 + l) << 3));
            acc[nt] = __builtin_amdgcn_mfma_f32_16x16x32_bf16(aW, b, acc[nt], 0, 0, 0);
        }
    }
    if (ok) {
        float* pc = C + (size_t)n * HD + q * 4;
        #pragma unroll
        for (int nt = 0; nt < 8; ++nt) {
            const int col = nt * 16 + q * 4;
            float4 bv = bias ? *(const float4*)(bias + col) : make_float4(0.f,0.f,0.f,0.f);
            float4 o;
            o.x = acc[nt][0] + bv.x; o.y = acc[nt][1] + bv.y;
            o.z = acc[nt][2] + bv.z; o.w = acc[nt][3] + bv.w;
            *(float4*)(pc + nt * 16) = o;
        }
    }
}

// ---- transposed dual GEMM, bf16 outputs: C0 = bf16(A@W0 + b0), C1 = bf16(A@W1) ----
template<int KB>
__global__ void __launch_bounds__(256) k_gemm2_Tb(const float* A,
        const unsigned short* __restrict__ W0, const unsigned short* __restrict__ W1,
        const float* __restrict__ b0, unsigned short* C0, unsigned short* C1, int M)
{
    const int t = threadIdx.x, w = t >> 6, l = t & 63;
    const int n = blockIdx.x * 64 + w * 16 + (l & 15);
    const bool ok = n < M;
    const int q = l >> 4;
    const int K = KB * 32;
    f32x4 a0[8] = {}, a1[8] = {};
    #pragma unroll
    for (int kb = 0; kb < KB; ++kb) {
        const bf16x8 b = load_a8(A + (size_t)n * K + kb * 32 + q * 8, ok);
        #pragma unroll
        for (int nt = 0; nt < 8; ++nt) {
            const bf16x8 u = *(const bf16x8*)(W0 + (((size_t)(kb * 8 + nt) * 64 + l) << 3));
            const bf16x8 v = *(const bf16x8*)(W1 + (((size_t)(kb * 8 + nt) * 64 + l) << 3));
            a0[nt] = __builtin_amdgcn_mfma_f32_16x16x32_bf16(u, b, a0[nt], 0, 0, 0);
            a1[nt] = __builtin_amdgcn_mfma_f32_16x16x32_bf16(v, b, a1[nt], 0, 0, 0);
        }
    }
    if (ok) {
        unsigned short* p0 = C0 + (size_t)n * HD + q * 4;
        unsigned short* p1 = C1 + (size_t)n * HD + q * 4;
        #pragma unroll
        for (int nt = 0; nt < 8; ++nt) {
            const int col = nt * 16 + q * 4;
            float4 bv = b0 ? *(const float4*)(b0 + col) : make_float4(0.f,0.f,0.f,0.f);
            float4 o0, o1;
            o0.x = a0[nt][0] + bv.x; o0.y = a0[nt][1] + bv.y;
            o0.z = a0[nt][2] + bv.z; o0.w = a0[nt][3] + bv.w;
            o1.x = a1[nt][0]; o1.y = a1[nt][1]; o1.z = a1[nt][2]; o1.w = a1[nt][3];
            *(bf16x4*)(p0 + nt * 16) = pack4(o0);
            *(bf16x4*)(p1 + nt * 16) = pack4(o1);
        }
    }
}

// ---- degree count ----
__global__ void __launch_bounds__(256) k_count(const int* __restrict__ d, int* __restrict__ cnt, int E)
{
    const int e = blockIdx.x * 256 + threadIdx.x;
    if (e < E) atomicAdd(&cnt[d[e]], 1);
}

// ---- mean(log(cnt+1)) numerator ----
__global__ void __launch_bounds__(256) k_avglog(const int* __restrict__ cnt, float* __restrict__ stats)
{
    float s = 0.f;
    for (int n = blockIdx.x * 256 + threadIdx.x; n < NN; n += gridDim.x * 256)
        s += logf((float)cnt[n] + 1.f);
    #pragma unroll
    for (int off = 32; off > 0; off >>= 1) s += __shfl_down(s, off);
    __shared__ float ls[4];
    if ((threadIdx.x & 63) == 0) ls[threadIdx.x >> 6] = s;
    __syncthreads();
    if (threadIdx.x == 0) unsafeAtomicAdd(stats, ls[0] + ls[1] + ls[2] + ls[3]);
}

// ---- CSR build ----
__global__ void __launch_bounds__(256) k_scan_block(const int* __restrict__ cnt,
        int* __restrict__ incl, int* __restrict__ part)
{
    __shared__ int s[256];
    const int t = threadIdx.x;
    const int i = blockIdx.x * 256 + t;
    const int v = (i < NN) ? cnt[i] : 0;
    s[t] = v;
    __syncthreads();
    #pragma unroll
    for (int off = 1; off < 256; off <<= 1) {
        const int x = (t >= off) ? s[t - off] : 0;
        __syncthreads();
        s[t] += x;
        __syncthreads();
    }
    if (i < NN) incl[i] = s[t];
    if (t == 255) part[blockIdx.x] = s[255];
}

__global__ void __launch_bounds__(256) k_scan_part(const int* __restrict__ part,
        int* __restrict__ poff, int np)
{
    __shared__ int s[256];
    const int t = threadIdx.x;
    const int v = (t < np) ? part[t] : 0;
    s[t] = v;
    __syncthreads();
    #pragma unroll
    for (int off = 1; off < 256; off <<= 1) {
        const int x = (t >= off) ? s[t - off] : 0;
        __syncthreads();
        s[t] += x;
        __syncthreads();
    }
    poff[t] = s[t] - v;
}

__global__ void __launch_bounds__(256) k_scan_add(const int* __restrict__ incl,
        const int* __restrict__ cnt, const int* __restrict__ poff,
        int* __restrict__ row_start, int* __restrict__ cursor)
{
    const int i = blockIdx.x * 256 + threadIdx.x;
    if (i < NN) {
        const int excl = incl[i] - cnt[i] + poff[blockIdx.x];
        row_start[i] = excl;
        cursor[i] = excl;
    }
    if (i == 0) row_start[NN] = NE;
}

__global__ void __launch_bounds__(256) k_scatter(const int* __restrict__ dstp,
        int* cursor, int* __restrict__ sppos)
{
    const int e = blockIdx.x * 256 + threadIdx.x;
    if (e < NE) sppos[e] = atomicAdd(&cursor[dstp[e]], 1);
}

// ---- transposed msg: m' = EA@W (+bias) + xs[src]; bf16 row-scatter to mbuf[sppos] ----
template<int KB>
__global__ void __launch_bounds__(256) k_msg_T(const float* __restrict__ EA,
        const unsigned short* __restrict__ Wpk, const float* __restrict__ bias,
        const unsigned short* __restrict__ xsb, const int* __restrict__ srcp,
        const int* __restrict__ sppos, unsigned short* __restrict__ mbuf)
{
    const int t = threadIdx.x, w = t >> 6, l = t & 63;
    const int e = blockIdx.x * 64 + w * 16 + (l & 15);
    const int q = l >> 4;
    f32x4 acc[8] = {};
    #pragma unroll
    for (int kb = 0; kb < KB; ++kb) {
        const bf16x8 bea = load_a8(EA + (size_t)e * (KB * 32) + kb * 32 + q * 8, true);
        #pragma unroll
        for (int nt = 0; nt < 8; ++nt) {
            const bf16x8 aW = *(const bf16x8*)(Wpk + (((size_t)(kb * 8 + nt) * 64 + l) << 3));
            acc[nt] = __builtin_amdgcn_mfma_f32_16x16x32_bf16(aW, bea, acc[nt], 0, 0, 0);
        }
    }
    const int sn = srcp[e], sp = sppos[e];
    const unsigned short* ps = xsb + (size_t)sn * HD + q * 4;
    unsigned short* pm = mbuf + (size_t)sp * HD + q * 4;
    #pragma unroll
    for (int nt = 0; nt < 8; ++nt) {
        const uint2 su = *(const uint2*)(ps + nt * 16);
        float4 o;
        o.x = acc[nt][0] + bflo2f(su.x); o.y = acc[nt][1] + bfhi2f(su.x);
        o.z = acc[nt][2] + bflo2f(su.y); o.w = acc[nt][3] + bfhi2f(su.y);
        if (bias) {
            const float4 bv = *(const float4*)(bias + nt * 16 + q * 4);
            o.x += bv.x; o.y += bv.y; o.z += bv.z; o.w += bv.w;
        }
        *(bf16x4*)(pm + nt * 16) = pack4(o);
    }
}

// ---- CSR aggregation; shift by xd[n] (bf16); writes [agg | agg*amp | agg*att] bf16 [NN][1536] ----
__global__ void __launch_bounds__(256) k_agg(const unsigned short* __restrict__ mbuf,
        const int* __restrict__ rs, const unsigned short* __restrict__ xdb,
        const float* __restrict__ stats, unsigned short* __restrict__ aggb)
{
    const int n = blockIdx.x * 4 + (threadIdx.x >> 6);
    if (n >= NN) return;
    const int lane = threadIdx.x & 63;
    const int c = lane * 2;
    const int s = rs[n], e = rs[n + 1];
    const unsigned xu = *(const unsigned*)(xdb + (size_t)n * HD + c);
    const float xv0 = bflo2f(xu), xv1 = bfhi2f(xu);
    float s0=0.f, s1=0.f, q0=0.f, q1=0.f;
    float mn0=INFINITY, mn1=INFINITY, mx0=-INFINITY, mx1=-INFINITY;
    for (int i = s; i < e; ++i) {
        const unsigned u = *(const unsigned*)(mbuf + (size_t)i * HD + c);
        const float v0 = bflo2f(u), v1 = bfhi2f(u);
        s0 += v0; s1 += v1;
        q0 += v0 * v0; q1 += v1 * v1;
        mn0 = fminf(mn0, v0); mn1 = fminf(mn1, v1);
        mx0 = fmaxf(mx0, v0); mx1 = fmaxf(mx1, v1);
    }
    const int deg = e - s;
    const float inv = 1.f / (float)(deg > 1 ? deg : 1);
    const float fd = (float)deg * inv;
    const float m0p = s0 * inv, m1p = s1 * inv;
    const float sd0 = sqrtf(fmaxf(q0 * inv - m0p * m0p, 0.f) + 1e-5f);
    const float sd1 = sqrtf(fmaxf(q1 * inv - m1p * m1p, 0.f) + 1e-5f);
    const bool has = deg > 0;
    const float v0[4] = { m0p + fd * xv0, has ? mn0 + xv0 : 0.f,
                          has ? mx0 + xv0 : 0.f, sd0 };
    const float v1[4] = { m1p + fd * xv1, has ? mn1 + xv1 : 0.f,
                          has ? mx1 + xv1 : 0.f, sd1 };
    const float avg = stats[0] * (1.f / (float)NN);
    const float lg = logf(fmaxf((float)deg, 1.f) + 1.f);
    const float amp = lg / avg, att = avg / lg;
    unsigned* a = (unsigned*)(aggb + (size_t)n * 1536 + c);
    #pragma unroll
    for (int sct = 0; sct < 4; ++sct) {
        a[sct * 64]       = (unsigned)f2bf(v0[sct])       | ((unsigned)f2bf(v1[sct]) << 16);
        a[256 + sct * 64] = (unsigned)f2bf(v0[sct] * amp) | ((unsigned)f2bf(v1[sct] * amp) << 16);
        a[512 + sct * 64] = (unsigned)f2bf(v0[sct] * att) | ((unsigned)f2bf(v1[sct] * att) << 16);
    }
}

// ---- transposed post+lin: out = [x|agg3]@PW + pb; outb = out@linW + lb ----
__global__ void __launch_bounds__(256) k_post_lin_T(const float* __restrict__ x,
        const unsigned short* __restrict__ aggb, const unsigned short* __restrict__ PWpk,
        const float* __restrict__ pb, const unsigned short* __restrict__ LNpk,
        const float* __restrict__ lb, float* __restrict__ outb, int M)
{
    __shared__ unsigned short s_o16[64 * 128];
    const int t = threadIdx.x, w = t >> 6, l = t & 63;
    const int el = w * 16 + (l & 15);
    const int n = blockIdx.x * 64 + el;
    const bool ok = n < M;
    const int q = l >> 4;
    f32x4 acc[8] = {};
    #pragma unroll
    for (int kb = 0; kb < 4; ++kb) {
        const bf16x8 b = load_a8(x + (size_t)n * HD + kb * 32 + q * 8, ok);
        #pragma unroll
        for (int nt = 0; nt < 8; ++nt) {
            const bf16x8 aW = *(const bf16x8*)(PWpk + (((size_t)(kb * 8 + nt) * 64 + l) << 3));
            acc[nt] = __builtin_amdgcn_mfma_f32_16x16x32_bf16(aW, b, acc[nt], 0, 0, 0);
        }
    }
    const unsigned short* arow = aggb + (size_t)n * 1536 + q * 8;
    #pragma unroll 4
    for (int kb = 4; kb < 52; ++kb) {
        bf16x8 b = {};
        if (ok) b = *(const bf16x8*)(arow + (size_t)(kb - 4) * 32);
        #pragma unroll
        for (int nt = 0; nt < 8; ++nt) {
            const bf16x8 aW = *(const bf16x8*)(PWpk + (((size_t)(kb * 8 + nt) * 64 + l) << 3));
            acc[nt] = __builtin_amdgcn_mfma_f32_16x16x32_bf16(aW, b, acc[nt], 0, 0, 0);
        }
    }
    #pragma unroll
    for (int nt = 0; nt < 8; ++nt) {
        const int col = nt * 16 + q * 4;
        const float4 bv = *(const float4*)(pb + col);
        float4 o;
        o.x = acc[nt][0] + bv.x; o.y = acc[nt][1] + bv.y;
        o.z = acc[nt][2] + bv.z; o.w = acc[nt][3] + bv.w;
        const int bcol = nt * 32 + q * 8;
        const int slot = bcol >> 4;
        const int ba = el * 256 + ((slot ^ (el & 7)) << 4) + (bcol & 15);
        *(bf16x4*)((char*)s_o16 + ba) = pack4(o);
    }
    __syncthreads();
    f32x4 acc2[8] = {};
    #pragma unroll
    for (int kb = 0; kb < 4; ++kb) {
        const int slot = kb * 4 + q;
        const int ba = el * 256 + ((slot ^ (el & 7)) << 4);
        const bf16x8 bh = *(const bf16x8*)((const char*)s_o16 + ba);
        #pragma unroll
        for (int nt = 0; nt < 8; ++nt) {
            const bf16x8 aW = *(const bf16x8*)(LNpk + (((size_t)(kb * 8 + nt) * 64 + l) << 3));
            acc2[nt] = __builtin_amdgcn_mfma_f32_16x16x32_bf16(aW, bh, acc2[nt], 0, 0, 0);
        }
    }
    if (ok) {
        float* pc = outb + (size_t)n * HD + q * 4;
        #pragma unroll
        for (int nt = 0; nt < 8; ++nt) {
            const int col = nt * 16 + q * 4;
            const float4 bv = *(const float4*)(lb + col);
            float4 o;
            o.x = acc2[nt][0] + bv.x; o.y = acc2[nt][1] + bv.y;
            o.z = acc2[nt][2] + bv.z; o.w = acc2[nt][3] + bv.w;
            *(float4*)(pc + nt * 16) = o;
        }
    }
}

// ---- BN column sums ----
__global__ void __launch_bounds__(256) k_bnstats(const float* __restrict__ ob,
        float* __restrict__ bs, float* __restrict__ bq, int M)
{
    const int c = threadIdx.x & 127;
    const int gsub = threadIdx.x >> 7;
    float s = 0.f, qq = 0.f;
    for (int rr = blockIdx.x * 2 + gsub; rr < M; rr += gridDim.x * 2) {
        const float v = ob[(size_t)rr * HD + c];
        s += v; qq += v * v;
    }
    __shared__ float ls[2][HD], lq[2][HD];
    ls[gsub][c] = s; lq[gsub][c] = qq;
    __syncthreads();
    if (gsub == 0) {
        unsafeAtomicAdd(&bs[c], ls[0][c] + ls[1][c]);
        unsafeAtomicAdd(&bq[c], lq[0][c] + lq[1][c]);
    }
}

// ---- x = (x + relu(bn(out)))/2 ----
__global__ void __launch_bounds__(256) k_xupdate(float* x, const float* __restrict__ ob,
        const float* __restrict__ bs, const float* __restrict__ bq,
        const float* __restrict__ g, const float* __restrict__ bb)
{
    const int i = blockIdx.x * 256 + threadIdx.x;
    const int c0 = (i & 31) * 4;
    const float4 ov = ((const float4*)ob)[i];
    const float4 xv = ((const float4*)x)[i];
    const float o[4]  = {ov.x, ov.y, ov.z, ov.w};
    const float xo[4] = {xv.x, xv.y, xv.z, xv.w};
    float res[4];
    #pragma unroll
    for (int j = 0; j < 4; ++j) {
        const int c = c0 + j;
        const float mu  = bs[c] * (1.f / (float)NN);
        const float var = bq[c] * (1.f / (float)NN) - mu * mu;
        const float bn  = g[c] * (o[j] - mu) * rsqrtf(var + 1e-5f) + bb[c];
        res[j] = (xo[j] + fmaxf(bn, 0.f)) * 0.5f;
    }
    ((float4*)x)[i] = make_float4(res[0], res[1], res[2], res[3]);
}

// ---- transposed edge update (final layer, standalone) ----
__global__ void __launch_bounds__(256) k_edge_upd_T(float* ea,
        const unsigned short* __restrict__ W1epk, const unsigned short* __restrict__ e2pk,
        const float* __restrict__ e2b, const unsigned short* __restrict__ xs1b,
        const unsigned short* __restrict__ xd1b, const int* __restrict__ srcp,
        const int* __restrict__ dstp)
{
    __shared__ unsigned short s_hid[64 * 128];
    __shared__ float s_b2[128];
    const int t = threadIdx.x, w = t >> 6, l = t & 63;
    const int row0b = blockIdx.x * 64;
    if (t < 128) s_b2[t] = e2b[t];
    const int el = w * 16 + (l & 15);
    const int e = row0b + el;
    const int q = l >> 4, kq = q * 8;
    f32x4 acc1[8] = {};
    #pragma unroll
    for (int kb = 0; kb < 4; ++kb) {
        const bf16x8 bea = load_a8(ea + (size_t)e * HD + kb * 32 + kq, true);
        #pragma unroll
        for (int nt = 0; nt < 8; ++nt) {
            const bf16x8 aW = *(const bf16x8*)(W1epk + (((size_t)(kb * 8 + nt) * 64 + l) << 3));
            acc1[nt] = __builtin_amdgcn_mfma_f32_16x16x32_bf16(aW, bea, acc1[nt], 0, 0, 0);
        }
    }
    {
        const int sn = srcp[e], dn = dstp[e];
        const unsigned short* ps = xs1b + (size_t)sn * HD + q * 4;
        const unsigned short* pd = xd1b + (size_t)dn * HD + q * 4;
        #pragma unroll
        for (int nt = 0; nt < 8; ++nt) {
            const uint2 su = *(const uint2*)(ps + nt * 16);
            const uint2 du = *(const uint2*)(pd + nt * 16);
            float4 h;
            h.x = fmaxf(acc1[nt][0] + bflo2f(su.x) + bflo2f(du.x), 0.f);
            h.y = fmaxf(acc1[nt][1] + bfhi2f(su.x) + bfhi2f(du.x), 0.f);
            h.z = fmaxf(acc1[nt][2] + bflo2f(su.y) + bflo2f(du.y), 0.f);
            h.w = fmaxf(acc1[nt][3] + bfhi2f(su.y) + bfhi2f(du.y), 0.f);
            const int bcol = nt * 32 + q * 8;
            const int slot = bcol >> 4;
            const int ba = el * 256 + ((slot ^ (el & 7)) << 4) + (bcol & 15);
            *(bf16x4*)((char*)s_hid + ba) = pack4(h);
        }
    }
    __syncthreads();
    f32x4 acc2[8] = {};
    #pragma unroll
    for (int kb = 0; kb < 4; ++kb) {
        const int slot = kb * 4 + q;
        const int ba = el * 256 + ((slot ^ (el & 7)) << 4);
        const bf16x8 bh = *(const bf16x8*)((const char*)s_hid + ba);
        #pragma unroll
        for (int nt = 0; nt < 8; ++nt) {
            const bf16x8 aW = *(const bf16x8*)(e2pk + (((size_t)(kb * 8 + nt) * 64 + l) << 3));
            acc2[nt] = __builtin_amdgcn_mfma_f32_16x16x32_bf16(aW, bh, acc2[nt], 0, 0, 0);
        }
    }
    {
        float* pe = ea + (size_t)e * HD + q * 4;
        #pragma unroll
        for (int nt = 0; nt < 8; ++nt) {
            const float4 eo = *(const float4*)(pe + nt * 16);
            const float4 bv = *(const float4*)(&s_b2[nt * 16 + q * 4]);
            float4 o;
            o.x = eo.x + (acc2[nt][0] + bv.x) * 0.5f;
            o.y = eo.y + (acc2[nt][1] + bv.y) * 0.5f;
            o.z = eo.z + (acc2[nt][2] + bv.z) * 0.5f;
            o.w = eo.w + (acc2[nt][3] + bv.w) * 0.5f;
            *(float4*)(pe + nt * 16) = o;
        }
    }
}

// ---- FUSED: edge_upd(l) + msg(l+1). ea -> ea'; mbuf = bf16(ea'@WeN + xsN[src]) ----
__global__ void __launch_bounds__(256) k_edge_msg_fused(float* ea,
        const unsigned short* __restrict__ W1epk, const unsigned short* __restrict__ e2pk,
        const float* __restrict__ e2b,
        const unsigned short* __restrict__ xs1b, const unsigned short* __restrict__ xd1b,
        const unsigned short* __restrict__ WeNpk, const unsigned short* __restrict__ xsNb,
        const int* __restrict__ srcp, const int* __restrict__ dstp,
        const int* __restrict__ sppos, unsigned short* __restrict__ mbuf)
{
    __shared__ unsigned short s_hid[64 * 128];   // swizzled bf16 hid tile
    __shared__ unsigned short s_ea1[64 * 128];   // swizzled bf16 updated-ea tile
    __shared__ float s_b2[128];
    const int t = threadIdx.x, w = t >> 6, l = t & 63;
    const int row0b = blockIdx.x * 64;
    if (t < 128) s_b2[t] = e2b[t];
    const int el = w * 16 + (l & 15);
    const int e = row0b + el;
    const int q = l >> 4, kq = q * 8;
    const int sn = srcp[e], dn = dstp[e];
    // GEMM1: W1e^T @ ea^T
    f32x4 acc1[8] = {};
    #pragma unroll
    for (int kb = 0; kb < 4; ++kb) {
        const bf16x8 bea = load_a8(ea + (size_t)e * HD + kb * 32 + kq, true);
        #pragma unroll
        for (int nt = 0; nt < 8; ++nt) {
            const bf16x8 aW = *(const bf16x8*)(W1epk + (((size_t)(kb * 8 + nt) * 64 + l) << 3));
            acc1[nt] = __builtin_amdgcn_mfma_f32_16x16x32_bf16(aW, bea, acc1[nt], 0, 0, 0);
        }
    }
    // epilogue1: hid = relu(acc1 + xs1[src] + xd1[dst]) -> s_hid
    {
        const unsigned short* ps = xs1b + (size_t)sn * HD + q * 4;
        const unsigned short* pd = xd1b + (size_t)dn * HD + q * 4;
        #pragma unroll
        for (int nt = 0; nt < 8; ++nt) {
            const uint2 su = *(const uint2*)(ps + nt * 16);
            const uint2 du = *(const uint2*)(pd + nt * 16);
            float4 h;
            h.x = fmaxf(acc1[nt][0] + bflo2f(su.x) + bflo2f(du.x), 0.f);
            h.y = fmaxf(acc1[nt][1] + bfhi2f(su.x) + bfhi2f(du.x), 0.f);
            h.z = fmaxf(acc1[nt][2] + bflo2f(su.y) + bflo2f(du.y), 0.f);
            h.w = fmaxf(acc1[nt][3] + bfhi2f(su.y) + bfhi2f(du.y), 0.f);
            const int bcol = nt * 32 + q * 8;
            const int slot = bcol >> 4;
            const int ba = el * 256 + ((slot ^ (el & 7)) << 4) + (bcol & 15);
            *(bf16x4*)((char*)s_hid + ba) = pack4(h);
        }
    }
    __syncthreads();
    // GEMM2: em2^T @ hid^T
    f32x4 acc2[8] = {};
    #pragma unroll
    for (int kb = 0; kb < 4; ++kb) {
        const int slot = kb * 4 + q;
        const int ba = el * 256 + ((slot ^ (el & 7)) << 4);
        const bf16x8 bh = *(const bf16x8*)((const char*)s_hid + ba);
        #pragma unroll
        for (int nt = 0; nt < 8; ++nt) {
            const bf16x8 aW = *(const bf16x8*)(e2pk + (((size_t)(kb * 8 + nt) * 64 + l) << 3));
            acc2[nt] = __builtin_amdgcn_mfma_f32_16x16x32_bf16(aW, bh, acc2[nt], 0, 0, 0);
        }
    }
    // epilogue2: ea' = ea_old + (acc2 + e2b)/2 -> global fp32 + s_ea1 bf16
    {
        float* pe = ea + (size_t)e * HD + q * 4;
        #pragma unroll
        for (int nt = 0; nt < 8; ++nt) {
            const float4 eo = *(const float4*)(pe + nt * 16);
            const float4 bv = *(const float4*)(&s_b2[nt * 16 + q * 4]);
            float4 o;
            o.x = eo.x + (acc2[nt][0] + bv.x) * 0.5f;
            o.y = eo.y + (acc2[nt][1] + bv.y) * 0.5f;
            o.z = eo.z + (acc2[nt][2] + bv.z) * 0.5f;
            o.w = eo.w + (acc2[nt][3] + bv.w) * 0.5f;
            *(float4*)(pe + nt * 16) = o;
            const int bcol = nt * 32 + q * 8;
            const int slot = bcol >> 4;
            const int ba = el * 256 + ((slot ^ (el & 7)) << 4) + (bcol & 15);
            *(bf16x4*)((char*)s_ea1 + ba) = pack4(o);
        }
    }
    __syncthreads();
    // GEMM3: WeN^T @ ea'^T (B-frag from s_ea1 at kq layout)
    f32x4 acc3[8] = {};
    #pragma unroll
    for (int kb = 0; kb < 4; ++kb) {
        const int slot = kb * 4 + q;
        const int ba = el * 256 + ((slot ^ (el & 7)) << 4);
        const bf16x8 be = *(const bf16x8*)((const char*)s_ea1 + ba);
        #pragma unroll
        for (int nt = 0; nt < 8; ++nt) {
            const bf16x8 aW = *(const bf16x8*)(WeNpk + (((size_t)(kb * 8 + nt) * 64 + l) << 3));
            acc3[nt] = __builtin_amdgcn_mfma_f32_16x16x32_bf16(aW, be, acc3[nt], 0, 0, 0);
        }
    }
    // epilogue3: m = acc3 + xsN[src]; bf16 scatter to mbuf[sppos]
    {
        const int sp = sppos[e];
        const unsigned short* ps = xsNb + (size_t)sn * HD + q * 4;
        unsigned short* pm = mbuf + (size_t)sp * HD + q * 4;
        #pragma unroll
        for (int nt = 0; nt < 8; ++nt) {
            const uint2 su = *(const uint2*)(ps + nt * 16);
            float4 o;
            o.x = acc3[nt][0] + bflo2f(su.x); o.y = acc3[nt][1] + bfhi2f(su.x);
            o.z = acc3[nt][2] + bflo2f(su.y); o.w = acc3[nt][3] + bfhi2f(su.y);
            *(bf16x4*)(pm + nt * 16) = pack4(o);
        }
    }
}

extern "C" void kernel_launch(void* const* d_in, const int* in_sizes, int n_in,
                              void* d_out, int out_size, void* d_ws, size_t ws_size,
                              hipStream_t stream)
{
    const float* x0    = (const float*)d_in[0];
    const float* eatr  = (const float*)d_in[1];
    const float* teatr = (const float*)d_in[2];
    const float* nodeW = (const float*)d_in[3];
    const float* nodeb = (const float*)d_in[4];
    const float* edgeW = (const float*)d_in[5];
    const float* edgeb = (const float*)d_in[6];
    const float* preW  = (const float*)d_in[7];
    const float* preb  = (const float*)d_in[8];
    const float* postW = (const float*)d_in[9];
    const float* postb = (const float*)d_in[10];
    const float* linW  = (const float*)d_in[11];
    const float* linb  = (const float*)d_in[12];
    const float* bng   = (const float*)d_in[13];
    const float* bnb   = (const float*)d_in[14];
    const float* em1W  = (const float*)d_in[15];
    const float* em1b  = (const float*)d_in[16];
    const float* em2W  = (const float*)d_in[17];
    const float* em2b  = (const float*)d_in[18];
    const int*   eidx  = (const int*)d_in[19];
    const int* srcp = eidx;
    const int* dstp = eidx + NE;

    float* out_x  = (float*)d_out;
    float* out_ea = out_x + (size_t)NN * HD;
    float* out_te = out_ea + (size_t)NE * HD;

    const size_t NH = (size_t)NN * HD;
    const size_t EH = (size_t)NE * HD;
    unsigned short* xdb  = (unsigned short*)d_ws;    // pre tables (bf16)
    unsigned short* xsb  = xdb + NH;
    unsigned short* xd1b = xsb + NH;                 // em1 tables (bf16)
    unsigned short* xs1b = xd1b + NH;
    float* outb  = (float*)(xs1b + NH);
    float* stats = outb + NH;
    float* Wf    = stats + 512;
    float* bfold = Wf + 4096;
    int*   cnt      = (int*)(bfold + 128);
    int*   row_start = cnt + NN;
    int*   cursor   = row_start + NN + 1;
    int*   tmpincl  = cursor + NN;
    int*   part     = tmpincl + NN;
    int*   poff     = part + 256;
    int*   sppos    = poff + 256;
    unsigned short* mbuf = (unsigned short*)(((uintptr_t)(sppos + NE) + 15) & ~(uintptr_t)15);
    unsigned short* aggb = mbuf + EH;
    unsigned short* pk   = aggb + (size_t)NN * 1536;
    const size_t KBSZ = 512 * 8;
    unsigned short* pkPost = pk;                       // 104 kbs
    unsigned short* pkPre  = pkPost + 104 * KBSZ;      // 24 kbs
    unsigned short* pkEm1  = pkPre  + 24 * KBSZ;       // 24 kbs
    unsigned short* pkLin  = pkEm1  + 24 * KBSZ;       // 8 kbs
    unsigned short* pkEm2  = pkLin  + 8 * KBSZ;        // 8 kbs
    unsigned short* pkNode = pkEm2  + 8 * KBSZ;        // 2 kbs
    unsigned short* pkEdge = pkNode + 2 * KBSZ;        // 1 kb
    unsigned short* pkWe0f = pkEdge + 1 * KBSZ;        // 1 kb

    hipMemsetAsync(cnt, 0, NN * sizeof(int), stream);
    hipMemsetAsync(stats, 0, 512 * sizeof(float), stream);

    k_packW<<<208, 256, 0, stream>>>(postW, pkPost, 3328);
    k_packW<<<48, 256, 0, stream>>>(preW,  pkPre,  768);
    k_packW<<<48, 256, 0, stream>>>(em1W,  pkEm1,  768);
    k_packW<<<16, 256, 0, stream>>>(linW,  pkLin,  256);
    k_packW<<<16, 256, 0, stream>>>(em2W,  pkEm2,  256);
    k_packW<<<4, 256, 0, stream>>>(nodeW, pkNode, 64);
    k_packW<<<2, 256, 0, stream>>>(edgeW, pkEdge, 32);
    k_foldW<<<17, 256, 0, stream>>>(edgeW, edgeb, preW + 256 * HD, Wf, bfold);
    k_packW<<<2, 256, 0, stream>>>(Wf, pkWe0f, 32);

    k_gemm_T<1><<<(NE + 63) / 64, 256, 0, stream>>>(eatr, pkEdge, edgeb, out_ea, NE);
    k_gemm_T<1><<<(NTE + 63) / 64, 256, 0, stream>>>(teatr, pkEdge, edgeb, out_te, NTE);
    k_gemm_T<2><<<(NN + 63) / 64, 256, 0, stream>>>(x0, pkNode, nodeb, out_x, NN);

    k_count<<<(NE + 255) / 256, 256, 0, stream>>>(dstp, cnt, NE);
    k_avglog<<<256, 256, 0, stream>>>(cnt, stats);
    k_scan_block<<<SCAN_B, 256, 0, stream>>>(cnt, tmpincl, part);
    k_scan_part<<<1, 256, 0, stream>>>(part, poff, SCAN_B);
    k_scan_add<<<SCAN_B, 256, 0, stream>>>(tmpincl, cnt, poff, row_start, cursor);
    k_scatter<<<(NE + 255) / 256, 256, 0, stream>>>(dstp, cursor, sppos);

    const int gn = (NN + 63) / 64;
    const int ge = NE / 64;

    // per-layer weight pointers
    const unsigned short *Wd_pk[NL], *Ws_pk[NL], *We_pk[NL];
    const unsigned short *W1s_pk[NL], *W1d_pk[NL], *W1e_pk[NL];
    const unsigned short *PW_pk[NL], *lin_pk[NL], *em2_pk[NL];
    for (int l = 0; l < NL; ++l) {
        Wd_pk[l]  = pkPre + (size_t)(l * 12 + 0) * KBSZ;
        Ws_pk[l]  = pkPre + (size_t)(l * 12 + 4) * KBSZ;
        We_pk[l]  = pkPre + (size_t)(l * 12 + 8) * KBSZ;
        W1s_pk[l] = pkEm1 + (size_t)(l * 12 + 0) * KBSZ;
        W1d_pk[l] = pkEm1 + (size_t)(l * 12 + 4) * KBSZ;
        W1e_pk[l] = pkEm1 + (size_t)(l * 12 + 8) * KBSZ;
        PW_pk[l]  = pkPost + (size_t)l * 52 * KBSZ;
        lin_pk[l] = pkLin + (size_t)l * 4 * KBSZ;
        em2_pk[l] = pkEm2 + (size_t)l * 4 * KBSZ;
    }

    // ---- layer 0 ----
    hipMemsetAsync(stats + 128, 0, 256 * sizeof(float), stream);
    k_gemm2_Tb<4><<<gn, 256, 0, stream>>>(out_x, Wd_pk[0], Ws_pk[0], preb, xdb, xsb, NN);
    k_msg_T<1><<<ge, 256, 0, stream>>>(eatr, pkWe0f, bfold, xsb, srcp, sppos, mbuf);
    k_agg<<<(NN + 3) / 4, 256, 0, stream>>>(mbuf, row_start, xdb, stats, aggb);
    k_post_lin_T<<<gn, 256, 0, stream>>>(out_x, aggb, PW_pk[0], postb, lin_pk[0], linb, outb, NN);
    k_bnstats<<<256, 256, 0, stream>>>(outb, stats + 128, stats + 256, NN);
    k_xupdate<<<NN * 32 / 256, 256, 0, stream>>>(out_x, outb, stats + 128, stats + 256, bng, bnb);
    k_gemm2_Tb<4><<<gn, 256, 0, stream>>>(out_x, W1d_pk[0], W1s_pk[0], em1b, xd1b, xs1b, NN);
    k_gemm2_Tb<4><<<gn, 256, 0, stream>>>(out_x, Wd_pk[1], Ws_pk[1], preb + HD, xdb, xsb, NN);
    // fused edge_upd(0) + msg(1)
    k_edge_msg_fused<<<ge, 256, 0, stream>>>(out_ea, W1e_pk[0], em2_pk[0], em2b,
                                             xs1b, xd1b, We_pk[1], xsb, srcp, dstp, sppos, mbuf);
    // ---- layer 1 ----
    hipMemsetAsync(stats + 128, 0, 256 * sizeof(float), stream);
    k_agg<<<(NN + 3) / 4, 256, 0, stream>>>(mbuf, row_start, xdb, stats, aggb);
    k_post_lin_T<<<gn, 256, 0, stream>>>(out_x, aggb, PW_pk[1], postb + HD, lin_pk[1], linb + HD, outb, NN);
    k_bnstats<<<256, 256, 0, stream>>>(outb, stats + 128, stats + 256, NN);
    k_xupdate<<<NN * 32 / 256, 256, 0, stream>>>(out_x, outb, stats + 128, stats + 256, bng + HD, bnb + HD);
    k_gemm2_Tb<4><<<gn, 256, 0, stream>>>(out_x, W1d_pk[1], W1s_pk[1], em1b + HD, xd1b, xs1b, NN);
    k_edge_upd_T<<<ge, 256, 0, stream>>>(out_ea, W1e_pk[1], em2_pk[1], em2b + HD, xs1b, xd1b, srcp, dstp);
}

// Round 10
// 1437.932 us; speedup vs baseline: 1.0178x; 1.0178x over previous
//
#include <hip/hip_runtime.h>
#include <math.h>

#define NN  50000
#define NE  400000
#define NTE 50000
#define FIN 64
#define EDIM 32
#define HD  128
#define NL  2
#define SCAN_B ((NN + 255) / 256)

typedef __attribute__((ext_vector_type(8))) short bf16x8;
typedef __attribute__((ext_vector_type(4))) short bf16x4;
typedef __attribute__((ext_vector_type(4))) float f32x4;

static __device__ __forceinline__ unsigned short f2bf(float f) {
    unsigned u = __float_as_uint(f);
    unsigned r = (u + 0x7fffu + ((u >> 16) & 1u)) >> 16;
    return (unsigned short)r;
}
static __device__ __forceinline__ float bfhi2f(unsigned u) { return __uint_as_float(u & 0xffff0000u); }
static __device__ __forceinline__ float bflo2f(unsigned u) { return __uint_as_float(u << 16); }

static __device__ __forceinline__ bf16x8 load_a8(const float* p, bool ok) {
    bf16x8 a = {};
    if (ok) {
        const float4 v0 = *(const float4*)(p);
        const float4 v1 = *(const float4*)(p + 4);
        a[0] = (short)f2bf(v0.x); a[1] = (short)f2bf(v0.y);
        a[2] = (short)f2bf(v0.z); a[3] = (short)f2bf(v0.w);
        a[4] = (short)f2bf(v1.x); a[5] = (short)f2bf(v1.y);
        a[6] = (short)f2bf(v1.z); a[7] = (short)f2bf(v1.w);
    }
    return a;
}
static __device__ __forceinline__ bf16x4 pack4(float4 a) {
    bf16x4 v;
    v[0]=(short)f2bf(a.x); v[1]=(short)f2bf(a.y); v[2]=(short)f2bf(a.z); v[3]=(short)f2bf(a.w);
    return v;
}
static __device__ __forceinline__ bf16x8 pack8(float4 a, float4 b) {
    bf16x8 v;
    v[0]=(short)f2bf(a.x); v[1]=(short)f2bf(a.y); v[2]=(short)f2bf(a.z); v[3]=(short)f2bf(a.w);
    v[4]=(short)f2bf(b.x); v[5]=(short)f2bf(b.y); v[6]=(short)f2bf(b.z); v[7]=(short)f2bf(b.w);
    return v;
}

// Fragment-major tables: col = nt*16 + q*4 + j stored at idx = q*32 + nt*4 + j.
// A lane (fixed q) owns one contiguous 64B span [q*32 .. q*32+31] per row.

// ---- pack fp32 W[K][128] into bf16 MFMA frag order ----
__global__ void __launch_bounds__(256) k_packW(const float* __restrict__ W,
        unsigned short* __restrict__ out, int K)
{
    const int tid = blockIdx.x * 256 + threadIdx.x;
    const int total = (K / 32) * 512;
    if (tid >= total) return;
    const int lane = tid & 63, nt = (tid >> 6) & 7, kb = tid >> 9;
    const int k0 = kb * 32 + (lane >> 4) * 8;
    const int col = nt * 16 + (lane & 15);
    bf16x8 v;
    #pragma unroll
    for (int j = 0; j < 8; ++j)
        v[j] = (short)f2bf(W[(size_t)(k0 + j) * HD + col]);
    *(bf16x8*)(out + (size_t)tid * 8) = v;
}

// ---- fold layer-0 message weight ----
__global__ void __launch_bounds__(256) k_foldW(const float* __restrict__ edgeW,
        const float* __restrict__ edgeb, const float* __restrict__ We0,
        float* __restrict__ Wf, float* __restrict__ bf)
{
    const int tid = blockIdx.x * 256 + threadIdx.x;
    if (tid < 4096) {
        const int k = tid >> 7, c = tid & 127;
        float s = 0.f;
        for (int j = 0; j < 128; ++j) s += edgeW[k * HD + j] * We0[(size_t)j * HD + c];
        Wf[tid] = s;
    } else if (tid < 4224) {
        const int c = tid - 4096;
        float s = 0.f;
        for (int j = 0; j < 128; ++j) s += edgeb[j] * We0[(size_t)j * HD + c];
        bf[c] = s;
    }
}

// ---- transposed MFMA GEMM (fp32 natural-order output) ----
template<int KB>
__global__ void __launch_bounds__(256) k_gemm_T(const float* A,
        const unsigned short* __restrict__ Wpk, const float* __restrict__ bias,
        float* C, int M)
{
    const int t = threadIdx.x, w = t >> 6, l = t & 63;
    const int n = blockIdx.x * 64 + w * 16 + (l & 15);
    const bool ok = n < M;
    const int q = l >> 4;
    const int K = KB * 32;
    f32x4 acc[8] = {};
    #pragma unroll
    for (int kb = 0; kb < KB; ++kb) {
        const bf16x8 b = load_a8(A + (size_t)n * K + kb * 32 + q * 8, ok);
        #pragma unroll
        for (int nt = 0; nt < 8; ++nt) {
            const bf16x8 aW = *(const bf16x8*)(Wpk + (((size_t)(kb * 8 + nt) * 64 + l) << 3));
            acc[nt] = __builtin_amdgcn_mfma_f32_16x16x32_bf16(aW, b, acc[nt], 0, 0, 0);
        }
    }
    if (ok) {
        float* pc = C + (size_t)n * HD + q * 4;
        #pragma unroll
        for (int nt = 0; nt < 8; ++nt) {
            const int col = nt * 16 + q * 4;
            float4 bv = bias ? *(const float4*)(bias + col) : make_float4(0.f,0.f,0.f,0.f);
            float4 o;
            o.x = acc[nt][0] + bv.x; o.y = acc[nt][1] + bv.y;
            o.z = acc[nt][2] + bv.z; o.w = acc[nt][3] + bv.w;
            *(float4*)(pc + nt * 16) = o;
        }
    }
}

// ---- transposed dual GEMM, bf16 FRAGMENT-MAJOR outputs ----
template<int KB>
__global__ void __launch_bounds__(256) k_gemm2_Tb(const float* A,
        const unsigned short* __restrict__ W0, const unsigned short* __restrict__ W1,
        const float* __restrict__ b0, unsigned short* C0, unsigned short* C1, int M)
{
    const int t = threadIdx.x, w = t >> 6, l = t & 63;
    const int n = blockIdx.x * 64 + w * 16 + (l & 15);
    const bool ok = n < M;
    const int q = l >> 4;
    const int K = KB * 32;
    f32x4 a0[8] = {}, a1[8] = {};
    #pragma unroll
    for (int kb = 0; kb < KB; ++kb) {
        const bf16x8 b = load_a8(A + (size_t)n * K + kb * 32 + q * 8, ok);
        #pragma unroll
        for (int nt = 0; nt < 8; ++nt) {
            const bf16x8 u = *(const bf16x8*)(W0 + (((size_t)(kb * 8 + nt) * 64 + l) << 3));
            const bf16x8 v = *(const bf16x8*)(W1 + (((size_t)(kb * 8 + nt) * 64 + l) << 3));
            a0[nt] = __builtin_amdgcn_mfma_f32_16x16x32_bf16(u, b, a0[nt], 0, 0, 0);
            a1[nt] = __builtin_amdgcn_mfma_f32_16x16x32_bf16(v, b, a1[nt], 0, 0, 0);
        }
    }
    if (ok) {
        unsigned short* p0 = C0 + (size_t)n * HD + q * 32;
        unsigned short* p1 = C1 + (size_t)n * HD + q * 32;
        #pragma unroll
        for (int k = 0; k < 4; ++k) {
            const int ntA = 2 * k, ntB = 2 * k + 1;
            float4 bA = b0 ? *(const float4*)(b0 + ntA * 16 + q * 4) : make_float4(0.f,0.f,0.f,0.f);
            float4 bB = b0 ? *(const float4*)(b0 + ntB * 16 + q * 4) : make_float4(0.f,0.f,0.f,0.f);
            float4 oA, oB;
            oA.x = a0[ntA][0]+bA.x; oA.y = a0[ntA][1]+bA.y; oA.z = a0[ntA][2]+bA.z; oA.w = a0[ntA][3]+bA.w;
            oB.x = a0[ntB][0]+bB.x; oB.y = a0[ntB][1]+bB.y; oB.z = a0[ntB][2]+bB.z; oB.w = a0[ntB][3]+bB.w;
            *(bf16x8*)(p0 + k * 8) = pack8(oA, oB);
            float4 uA = make_float4(a1[ntA][0], a1[ntA][1], a1[ntA][2], a1[ntA][3]);
            float4 uB = make_float4(a1[ntB][0], a1[ntB][1], a1[ntB][2], a1[ntB][3]);
            *(bf16x8*)(p1 + k * 8) = pack8(uA, uB);
        }
    }
}

// ---- degree count ----
__global__ void __launch_bounds__(256) k_count(const int* __restrict__ d, int* __restrict__ cnt, int E)
{
    const int e = blockIdx.x * 256 + threadIdx.x;
    if (e < E) atomicAdd(&cnt[d[e]], 1);
}

// ---- mean(log(cnt+1)) numerator ----
__global__ void __launch_bounds__(256) k_avglog(const int* __restrict__ cnt, float* __restrict__ stats)
{
    float s = 0.f;
    for (int n = blockIdx.x * 256 + threadIdx.x; n < NN; n += gridDim.x * 256)
        s += logf((float)cnt[n] + 1.f);
    #pragma unroll
    for (int off = 32; off > 0; off >>= 1) s += __shfl_down(s, off);
    __shared__ float ls[4];
    if ((threadIdx.x & 63) == 0) ls[threadIdx.x >> 6] = s;
    __syncthreads();
    if (threadIdx.x == 0) unsafeAtomicAdd(stats, ls[0] + ls[1] + ls[2] + ls[3]);
}

// ---- CSR build ----
__global__ void __launch_bounds__(256) k_scan_block(const int* __restrict__ cnt,
        int* __restrict__ incl, int* __restrict__ part)
{
    __shared__ int s[256];
    const int t = threadIdx.x;
    const int i = blockIdx.x * 256 + t;
    const int v = (i < NN) ? cnt[i] : 0;
    s[t] = v;
    __syncthreads();
    #pragma unroll
    for (int off = 1; off < 256; off <<= 1) {
        const int x = (t >= off) ? s[t - off] : 0;
        __syncthreads();
        s[t] += x;
        __syncthreads();
    }
    if (i < NN) incl[i] = s[t];
    if (t == 255) part[blockIdx.x] = s[255];
}

__global__ void __launch_bounds__(256) k_scan_part(const int* __restrict__ part,
        int* __restrict__ poff, int np)
{
    __shared__ int s[256];
    const int t = threadIdx.x;
    const int v = (t < np) ? part[t] : 0;
    s[t] = v;
    __syncthreads();
    #pragma unroll
    for (int off = 1; off < 256; off <<= 1) {
        const int x = (t >= off) ? s[t - off] : 0;
        __syncthreads();
        s[t] += x;
        __syncthreads();
    }
    poff[t] = s[t] - v;
}

__global__ void __launch_bounds__(256) k_scan_add(const int* __restrict__ incl,
        const int* __restrict__ cnt, const int* __restrict__ poff,
        int* __restrict__ row_start, int* __restrict__ cursor)
{
    const int i = blockIdx.x * 256 + threadIdx.x;
    if (i < NN) {
        const int excl = incl[i] - cnt[i] + poff[blockIdx.x];
        row_start[i] = excl;
        cursor[i] = excl;
    }
    if (i == 0) row_start[NN] = NE;
}

__global__ void __launch_bounds__(256) k_scatter(const int* __restrict__ dstp,
        int* cursor, int* __restrict__ sppos)
{
    const int e = blockIdx.x * 256 + threadIdx.x;
    if (e < NE) sppos[e] = atomicAdd(&cursor[dstp[e]], 1);
}

// ---- transposed msg: m' = EA@W (+bias) + xs[src]; fragment-major bf16 mbuf ----
template<int KB>
__global__ void __launch_bounds__(256) k_msg_T(const float* __restrict__ EA,
        const unsigned short* __restrict__ Wpk, const float* __restrict__ bias,
        const unsigned short* __restrict__ xsb, const int* __restrict__ srcp,
        const int* __restrict__ sppos, unsigned short* __restrict__ mbuf)
{
    const int t = threadIdx.x, w = t >> 6, l = t & 63;
    const int e = blockIdx.x * 64 + w * 16 + (l & 15);
    const int q = l >> 4;
    f32x4 acc[8] = {};
    #pragma unroll
    for (int kb = 0; kb < KB; ++kb) {
        const bf16x8 bea = load_a8(EA + (size_t)e * (KB * 32) + kb * 32 + q * 8, true);
        #pragma unroll
        for (int nt = 0; nt < 8; ++nt) {
            const bf16x8 aW = *(const bf16x8*)(Wpk + (((size_t)(kb * 8 + nt) * 64 + l) << 3));
            acc[nt] = __builtin_amdgcn_mfma_f32_16x16x32_bf16(aW, bea, acc[nt], 0, 0, 0);
        }
    }
    const int sn = srcp[e], sp = sppos[e];
    const unsigned short* ps = xsb + (size_t)sn * HD + q * 32;   // contiguous 64B
    unsigned short* pm = mbuf + (size_t)sp * HD + q * 32;        // contiguous 64B
    #pragma unroll
    for (int k = 0; k < 4; ++k) {
        const int ntA = 2 * k, ntB = 2 * k + 1;
        const uint4 su = *(const uint4*)(ps + k * 8);
        float4 oA, oB;
        oA.x = acc[ntA][0] + bflo2f(su.x); oA.y = acc[ntA][1] + bfhi2f(su.x);
        oA.z = acc[ntA][2] + bflo2f(su.y); oA.w = acc[ntA][3] + bfhi2f(su.y);
        oB.x = acc[ntB][0] + bflo2f(su.z); oB.y = acc[ntB][1] + bfhi2f(su.z);
        oB.z = acc[ntB][2] + bflo2f(su.w); oB.w = acc[ntB][3] + bfhi2f(su.w);
        if (bias) {
            const float4 bA = *(const float4*)(bias + ntA * 16 + q * 4);
            const float4 bB = *(const float4*)(bias + ntB * 16 + q * 4);
            oA.x += bA.x; oA.y += bA.y; oA.z += bA.z; oA.w += bA.w;
            oB.x += bB.x; oB.y += bB.y; oB.z += bB.z; oB.w += bB.w;
        }
        *(bf16x8*)(pm + k * 8) = pack8(oA, oB);
    }
}

// ---- CSR aggregation; fragment-major mbuf/xdb inputs; natural-order agg3 output ----
__global__ void __launch_bounds__(256) k_agg(const unsigned short* __restrict__ mbuf,
        const int* __restrict__ rs, const unsigned short* __restrict__ xdb,
        const float* __restrict__ stats, unsigned short* __restrict__ aggb)
{
    const int n = blockIdx.x * 4 + (threadIdx.x >> 6);
    if (n >= NN) return;
    const int lane = threadIdx.x & 63;
    const int c = lane * 2;
    // fragment-major index of col pair (c, c+1): idx = q*32 + nt*4 + j
    const int pidx = ((c & 12) << 3) + ((c >> 4) << 2) + (c & 3);
    const int s = rs[n], e = rs[n + 1];
    const unsigned xu = *(const unsigned*)(xdb + (size_t)n * HD + pidx);
    const float xv0 = bflo2f(xu), xv1 = bfhi2f(xu);
    float s0=0.f, s1=0.f, q0=0.f, q1=0.f;
    float mn0=INFINITY, mn1=INFINITY, mx0=-INFINITY, mx1=-INFINITY;
    for (int i = s; i < e; ++i) {
        const unsigned u = *(const unsigned*)(mbuf + (size_t)i * HD + pidx);
        const float v0 = bflo2f(u), v1 = bfhi2f(u);
        s0 += v0; s1 += v1;
        q0 += v0 * v0; q1 += v1 * v1;
        mn0 = fminf(mn0, v0); mn1 = fminf(mn1, v1);
        mx0 = fmaxf(mx0, v0); mx1 = fmaxf(mx1, v1);
    }
    const int deg = e - s;
    const float inv = 1.f / (float)(deg > 1 ? deg : 1);
    const float fd = (float)deg * inv;
    const float m0p = s0 * inv, m1p = s1 * inv;
    const float sd0 = sqrtf(fmaxf(q0 * inv - m0p * m0p, 0.f) + 1e-5f);
    const float sd1 = sqrtf(fmaxf(q1 * inv - m1p * m1p, 0.f) + 1e-5f);
    const bool has = deg > 0;
    const float v0[4] = { m0p + fd * xv0, has ? mn0 + xv0 : 0.f,
                          has ? mx0 + xv0 : 0.f, sd0 };
    const float v1[4] = { m1p + fd * xv1, has ? mn1 + xv1 : 0.f,
                          has ? mx1 + xv1 : 0.f, sd1 };
    const float avg = stats[0] * (1.f / (float)NN);
    const float lg = logf(fmaxf((float)deg, 1.f) + 1.f);
    const float amp = lg / avg, att = avg / lg;
    unsigned* a = (unsigned*)(aggb + (size_t)n * 1536 + c);
    #pragma unroll
    for (int sct = 0; sct < 4; ++sct) {
        a[sct * 64]       = (unsigned)f2bf(v0[sct])       | ((unsigned)f2bf(v1[sct]) << 16);
        a[256 + sct * 64] = (unsigned)f2bf(v0[sct] * amp) | ((unsigned)f2bf(v1[sct] * amp) << 16);
        a[512 + sct * 64] = (unsigned)f2bf(v0[sct] * att) | ((unsigned)f2bf(v1[sct] * att) << 16);
    }
}

// ---- transposed post+lin ----
__global__ void __launch_bounds__(256) k_post_lin_T(const float* __restrict__ x,
        const unsigned short* __restrict__ aggb, const unsigned short* __restrict__ PWpk,
        const float* __restrict__ pb, const unsigned short* __restrict__ LNpk,
        const float* __restrict__ lb, float* __restrict__ outb, int M)
{
    __shared__ unsigned short s_o16[64 * 128];
    const int t = threadIdx.x, w = t >> 6, l = t & 63;
    const int el = w * 16 + (l & 15);
    const int n = blockIdx.x * 64 + el;
    const bool ok = n < M;
    const int q = l >> 4;
    f32x4 acc[8] = {};
    #pragma unroll
    for (int kb = 0; kb < 4; ++kb) {
        const bf16x8 b = load_a8(x + (size_t)n * HD + kb * 32 + q * 8, ok);
        #pragma unroll
        for (int nt = 0; nt < 8; ++nt) {
            const bf16x8 aW = *(const bf16x8*)(PWpk + (((size_t)(kb * 8 + nt) * 64 + l) << 3));
            acc[nt] = __builtin_amdgcn_mfma_f32_16x16x32_bf16(aW, b, acc[nt], 0, 0, 0);
        }
    }
    const unsigned short* arow = aggb + (size_t)n * 1536 + q * 8;
    #pragma unroll 4
    for (int kb = 4; kb < 52; ++kb) {
        bf16x8 b = {};
        if (ok) b = *(const bf16x8*)(arow + (size_t)(kb - 4) * 32);
        #pragma unroll
        for (int nt = 0; nt < 8; ++nt) {
            const bf16x8 aW = *(const bf16x8*)(PWpk + (((size_t)(kb * 8 + nt) * 64 + l) << 3));
            acc[nt] = __builtin_amdgcn_mfma_f32_16x16x32_bf16(aW, b, acc[nt], 0, 0, 0);
        }
    }
    #pragma unroll
    for (int nt = 0; nt < 8; ++nt) {
        const int col = nt * 16 + q * 4;
        const float4 bv = *(const float4*)(pb + col);
        float4 o;
        o.x = acc[nt][0] + bv.x; o.y = acc[nt][1] + bv.y;
        o.z = acc[nt][2] + bv.z; o.w = acc[nt][3] + bv.w;
        const int bcol = nt * 32 + q * 8;
        const int slot = bcol >> 4;
        const int ba = el * 256 + ((slot ^ (el & 7)) << 4) + (bcol & 15);
        *(bf16x4*)((char*)s_o16 + ba) = pack4(o);
    }
    __syncthreads();
    f32x4 acc2[8] = {};
    #pragma unroll
    for (int kb = 0; kb < 4; ++kb) {
        const int slot = kb * 4 + q;
        const int ba = el * 256 + ((slot ^ (el & 7)) << 4);
        const bf16x8 bh = *(const bf16x8*)((const char*)s_o16 + ba);
        #pragma unroll
        for (int nt = 0; nt < 8; ++nt) {
            const bf16x8 aW = *(const bf16x8*)(LNpk + (((size_t)(kb * 8 + nt) * 64 + l) << 3));
            acc2[nt] = __builtin_amdgcn_mfma_f32_16x16x32_bf16(aW, bh, acc2[nt], 0, 0, 0);
        }
    }
    if (ok) {
        float* pc = outb + (size_t)n * HD + q * 4;
        #pragma unroll
        for (int nt = 0; nt < 8; ++nt) {
            const int col = nt * 16 + q * 4;
            const float4 bv = *(const float4*)(lb + col);
            float4 o;
            o.x = acc2[nt][0] + bv.x; o.y = acc2[nt][1] + bv.y;
            o.z = acc2[nt][2] + bv.z; o.w = acc2[nt][3] + bv.w;
            *(float4*)(pc + nt * 16) = o;
        }
    }
}

// ---- BN column sums ----
__global__ void __launch_bounds__(256) k_bnstats(const float* __restrict__ ob,
        float* __restrict__ bs, float* __restrict__ bq, int M)
{
    const int c = threadIdx.x & 127;
    const int gsub = threadIdx.x >> 7;
    float s = 0.f, qq = 0.f;
    for (int rr = blockIdx.x * 2 + gsub; rr < M; rr += gridDim.x * 2) {
        const float v = ob[(size_t)rr * HD + c];
        s += v; qq += v * v;
    }
    __shared__ float ls[2][HD], lq[2][HD];
    ls[gsub][c] = s; lq[gsub][c] = qq;
    __syncthreads();
    if (gsub == 0) {
        unsafeAtomicAdd(&bs[c], ls[0][c] + ls[1][c]);
        unsafeAtomicAdd(&bq[c], lq[0][c] + lq[1][c]);
    }
}

// ---- x = (x + relu(bn(out)))/2 ----
__global__ void __launch_bounds__(256) k_xupdate(float* x, const float* __restrict__ ob,
        const float* __restrict__ bs, const float* __restrict__ bq,
        const float* __restrict__ g, const float* __restrict__ bb)
{
    const int i = blockIdx.x * 256 + threadIdx.x;
    const int c0 = (i & 31) * 4;
    const float4 ov = ((const float4*)ob)[i];
    const float4 xv = ((const float4*)x)[i];
    const float o[4]  = {ov.x, ov.y, ov.z, ov.w};
    const float xo[4] = {xv.x, xv.y, xv.z, xv.w};
    float res[4];
    #pragma unroll
    for (int j = 0; j < 4; ++j) {
        const int c = c0 + j;
        const float mu  = bs[c] * (1.f / (float)NN);
        const float var = bq[c] * (1.f / (float)NN) - mu * mu;
        const float bn  = g[c] * (o[j] - mu) * rsqrtf(var + 1e-5f) + bb[c];
        res[j] = (xo[j] + fmaxf(bn, 0.f)) * 0.5f;
    }
    ((float4*)x)[i] = make_float4(res[0], res[1], res[2], res[3]);
}

// ---- transposed edge update (fragment-major gather tables) ----
__global__ void __launch_bounds__(256) k_edge_upd_T(float* ea,
        const unsigned short* __restrict__ W1epk, const unsigned short* __restrict__ e2pk,
        const float* __restrict__ e2b, const unsigned short* __restrict__ xs1b,
        const unsigned short* __restrict__ xd1b, const int* __restrict__ srcp,
        const int* __restrict__ dstp)
{
    __shared__ unsigned short s_hid[64 * 128];
    __shared__ float s_b2[128];
    const int t = threadIdx.x, w = t >> 6, l = t & 63;
    const int row0b = blockIdx.x * 64;
    if (t < 128) s_b2[t] = e2b[t];
    const int el = w * 16 + (l & 15);
    const int e = row0b + el;
    const int q = l >> 4, kq = q * 8;
    f32x4 acc1[8] = {};
    #pragma unroll
    for (int kb = 0; kb < 4; ++kb) {
        const bf16x8 bea = load_a8(ea + (size_t)e * HD + kb * 32 + kq, true);
        #pragma unroll
        for (int nt = 0; nt < 8; ++nt) {
            const bf16x8 aW = *(const bf16x8*)(W1epk + (((size_t)(kb * 8 + nt) * 64 + l) << 3));
            acc1[nt] = __builtin_amdgcn_mfma_f32_16x16x32_bf16(aW, bea, acc1[nt], 0, 0, 0);
        }
    }
    {
        const int sn = srcp[e], dn = dstp[e];
        const unsigned short* ps = xs1b + (size_t)sn * HD + q * 32;  // contiguous 64B
        const unsigned short* pd = xd1b + (size_t)dn * HD + q * 32;
        #pragma unroll
        for (int k = 0; k < 4; ++k) {
            const int ntA = 2 * k, ntB = 2 * k + 1;
            const uint4 su = *(const uint4*)(ps + k * 8);
            const uint4 du = *(const uint4*)(pd + k * 8);
            float4 hA, hB;
            hA.x = fmaxf(acc1[ntA][0] + bflo2f(su.x) + bflo2f(du.x), 0.f);
            hA.y = fmaxf(acc1[ntA][1] + bfhi2f(su.x) + bfhi2f(du.x), 0.f);
            hA.z = fmaxf(acc1[ntA][2] + bflo2f(su.y) + bflo2f(du.y), 0.f);
            hA.w = fmaxf(acc1[ntA][3] + bfhi2f(su.y) + bfhi2f(du.y), 0.f);
            hB.x = fmaxf(acc1[ntB][0] + bflo2f(su.z) + bflo2f(du.z), 0.f);
            hB.y = fmaxf(acc1[ntB][1] + bfhi2f(su.z) + bfhi2f(du.z), 0.f);
            hB.z = fmaxf(acc1[ntB][2] + bflo2f(su.w) + bflo2f(du.w), 0.f);
            hB.w = fmaxf(acc1[ntB][3] + bfhi2f(su.w) + bfhi2f(du.w), 0.f);
            const int bcolA = ntA * 32 + q * 8;
            const int baA = el * 256 + (((bcolA >> 4) ^ (el & 7)) << 4) + (bcolA & 15);
            *(bf16x4*)((char*)s_hid + baA) = pack4(hA);
            const int bcolB = ntB * 32 + q * 8;
            const int baB = el * 256 + (((bcolB >> 4) ^ (el & 7)) << 4) + (bcolB & 15);
            *(bf16x4*)((char*)s_hid + baB) = pack4(hB);
        }
    }
    __syncthreads();
    f32x4 acc2[8] = {};
    #pragma unroll
    for (int kb = 0; kb < 4; ++kb) {
        const int slot = kb * 4 + q;
        const int ba = el * 256 + ((slot ^ (el & 7)) << 4);
        const bf16x8 bh = *(const bf16x8*)((const char*)s_hid + ba);
        #pragma unroll
        for (int nt = 0; nt < 8; ++nt) {
            const bf16x8 aW = *(const bf16x8*)(e2pk + (((size_t)(kb * 8 + nt) * 64 + l) << 3));
            acc2[nt] = __builtin_amdgcn_mfma_f32_16x16x32_bf16(aW, bh, acc2[nt], 0, 0, 0);
        }
    }
    {
        float* pe = ea + (size_t)e * HD + q * 4;
        #pragma unroll
        for (int nt = 0; nt < 8; ++nt) {
            const float4 eo = *(const float4*)(pe + nt * 16);
            const float4 bv = *(const float4*)(&s_b2[nt * 16 + q * 4]);
            float4 o;
            o.x = eo.x + (acc2[nt][0] + bv.x) * 0.5f;
            o.y = eo.y + (acc2[nt][1] + bv.y) * 0.5f;
            o.z = eo.z + (acc2[nt][2] + bv.z) * 0.5f;
            o.w = eo.w + (acc2[nt][3] + bv.w) * 0.5f;
            *(float4*)(pe + nt * 16) = o;
        }
    }
}

extern "C" void kernel_launch(void* const* d_in, const int* in_sizes, int n_in,
                              void* d_out, int out_size, void* d_ws, size_t ws_size,
                              hipStream_t stream)
{
    const float* x0    = (const float*)d_in[0];
    const float* eatr  = (const float*)d_in[1];
    const float* teatr = (const float*)d_in[2];
    const float* nodeW = (const float*)d_in[3];
    const float* nodeb = (const float*)d_in[4];
    const float* edgeW = (const float*)d_in[5];
    const float* edgeb = (const float*)d_in[6];
    const float* preW  = (const float*)d_in[7];
    const float* preb  = (const float*)d_in[8];
    const float* postW = (const float*)d_in[9];
    const float* postb = (const float*)d_in[10];
    const float* linW  = (const float*)d_in[11];
    const float* linb  = (const float*)d_in[12];
    const float* bng   = (const float*)d_in[13];
    const float* bnb   = (const float*)d_in[14];
    const float* em1W  = (const float*)d_in[15];
    const float* em1b  = (const float*)d_in[16];
    const float* em2W  = (const float*)d_in[17];
    const float* em2b  = (const float*)d_in[18];
    const int*   eidx  = (const int*)d_in[19];
    const int* srcp = eidx;
    const int* dstp = eidx + NE;

    float* out_x  = (float*)d_out;
    float* out_ea = out_x + (size_t)NN * HD;
    float* out_te = out_ea + (size_t)NE * HD;

    const size_t NH = (size_t)NN * HD;
    const size_t EH = (size_t)NE * HD;
    unsigned short* xdb = (unsigned short*)d_ws;     // [NN][128] bf16, fragment-major
    unsigned short* xsb = xdb + NH;                  // [NN][128] bf16, fragment-major
    float* outb  = (float*)(xsb + NH);
    float* stats = outb + NH;
    float* Wf    = stats + 512;
    float* bfold = Wf + 4096;
    int*   cnt      = (int*)(bfold + 128);
    int*   row_start = cnt + NN;
    int*   cursor   = row_start + NN + 1;
    int*   tmpincl  = cursor + NN;
    int*   part     = tmpincl + NN;
    int*   poff     = part + 256;
    int*   sppos    = poff + 256;
    unsigned short* mbuf = (unsigned short*)(((uintptr_t)(sppos + NE) + 15) & ~(uintptr_t)15);
    unsigned short* aggb = mbuf + EH;                  // [NN][1536] bf16 natural
    unsigned short* pk   = aggb + (size_t)NN * 1536;
    const size_t KBSZ = 512 * 8;
    unsigned short* pkPost = pk;                       // 104 kbs
    unsigned short* pkPre  = pkPost + 104 * KBSZ;      // 24 kbs
    unsigned short* pkEm1  = pkPre  + 24 * KBSZ;       // 24 kbs
    unsigned short* pkLin  = pkEm1  + 24 * KBSZ;       // 8 kbs
    unsigned short* pkEm2  = pkLin  + 8 * KBSZ;        // 8 kbs
    unsigned short* pkNode = pkEm2  + 8 * KBSZ;        // 2 kbs
    unsigned short* pkEdge = pkNode + 2 * KBSZ;        // 1 kb
    unsigned short* pkWe0f = pkEdge + 1 * KBSZ;        // 1 kb

    hipMemsetAsync(cnt, 0, NN * sizeof(int), stream);
    hipMemsetAsync(stats, 0, 512 * sizeof(float), stream);

    k_packW<<<208, 256, 0, stream>>>(postW, pkPost, 3328);
    k_packW<<<48, 256, 0, stream>>>(preW,  pkPre,  768);
    k_packW<<<48, 256, 0, stream>>>(em1W,  pkEm1,  768);
    k_packW<<<16, 256, 0, stream>>>(linW,  pkLin,  256);
    k_packW<<<16, 256, 0, stream>>>(em2W,  pkEm2,  256);
    k_packW<<<4, 256, 0, stream>>>(nodeW, pkNode, 64);
    k_packW<<<2, 256, 0, stream>>>(edgeW, pkEdge, 32);
    k_foldW<<<17, 256, 0, stream>>>(edgeW, edgeb, preW + 256 * HD, Wf, bfold);
    k_packW<<<2, 256, 0, stream>>>(Wf, pkWe0f, 32);

    k_gemm_T<1><<<(NE + 63) / 64, 256, 0, stream>>>(eatr, pkEdge, edgeb, out_ea, NE);
    k_gemm_T<1><<<(NTE + 63) / 64, 256, 0, stream>>>(teatr, pkEdge, edgeb, out_te, NTE);
    k_gemm_T<2><<<(NN + 63) / 64, 256, 0, stream>>>(x0, pkNode, nodeb, out_x, NN);

    k_count<<<(NE + 255) / 256, 256, 0, stream>>>(dstp, cnt, NE);
    k_avglog<<<256, 256, 0, stream>>>(cnt, stats);
    k_scan_block<<<SCAN_B, 256, 0, stream>>>(cnt, tmpincl, part);
    k_scan_part<<<1, 256, 0, stream>>>(part, poff, SCAN_B);
    k_scan_add<<<SCAN_B, 256, 0, stream>>>(tmpincl, cnt, poff, row_start, cursor);
    k_scatter<<<(NE + 255) / 256, 256, 0, stream>>>(dstp, cursor, sppos);

    const int gn = (NN + 63) / 64;
    const int ge = NE / 64;

    for (int l = 0; l < NL; ++l) {
        const unsigned short* Wd_pk  = pkPre + (size_t)(l * 12 + 0) * KBSZ;
        const unsigned short* Ws_pk  = pkPre + (size_t)(l * 12 + 4) * KBSZ;
        const unsigned short* We_pk  = pkPre + (size_t)(l * 12 + 8) * KBSZ;
        const unsigned short* W1s_pk = pkEm1 + (size_t)(l * 12 + 0) * KBSZ;
        const unsigned short* W1d_pk = pkEm1 + (size_t)(l * 12 + 4) * KBSZ;
        const unsigned short* W1e_pk = pkEm1 + (size_t)(l * 12 + 8) * KBSZ;
        const unsigned short* PW_pk  = pkPost + (size_t)l * 52 * KBSZ;
        const unsigned short* lin_pk = pkLin + (size_t)l * 4 * KBSZ;
        const unsigned short* em2_pk = pkEm2 + (size_t)l * 4 * KBSZ;
        const float* pbl = preb + l * HD;
        const float* pob = postb + l * HD;
        const float* lb  = linb + l * HD;
        const float* g_  = bng + l * HD;
        const float* b_  = bnb + l * HD;
        const float* e1b = em1b + l * HD;
        const float* e2b = em2b + l * HD;

        hipMemsetAsync(stats + 128, 0, 256 * sizeof(float), stream);

        k_gemm2_Tb<4><<<gn, 256, 0, stream>>>(out_x, Wd_pk, Ws_pk, pbl, xdb, xsb, NN);
        if (l == 0)
            k_msg_T<1><<<ge, 256, 0, stream>>>(eatr, pkWe0f, bfold, xsb, srcp, sppos, mbuf);
        else
            k_msg_T<4><<<ge, 256, 0, stream>>>(out_ea, We_pk, nullptr, xsb, srcp, sppos, mbuf);
        k_agg<<<(NN + 3) / 4, 256, 0, stream>>>(mbuf, row_start, xdb, stats, aggb);
        k_post_lin_T<<<gn, 256, 0, stream>>>(out_x, aggb, PW_pk, pob, lin_pk, lb, outb, NN);
        k_bnstats<<<256, 256, 0, stream>>>(outb, stats + 128, stats + 256, NN);
        k_xupdate<<<NN * 32 / 256, 256, 0, stream>>>(out_x, outb, stats + 128, stats + 256, g_, b_);
        k_gemm2_Tb<4><<<gn, 256, 0, stream>>>(out_x, W1d_pk, W1s_pk, e1b, xdb, xsb, NN);
        k_edge_upd_T<<<ge, 256, 0, stream>>>(out_ea, W1e_pk, em2_pk, e2b, xsb, xdb, srcp, dstp);
    }
}

// Round 11
// 1333.805 us; speedup vs baseline: 1.0973x; 1.0781x over previous
//
#include <hip/hip_runtime.h>
#include <math.h>

#define NN  50000
#define NE  400000
#define NTE 50000
#define FIN 64
#define EDIM 32
#define HD  128
#define NL  2
#define SCAN_B ((NN + 255) / 256)

typedef __attribute__((ext_vector_type(8))) short bf16x8;
typedef __attribute__((ext_vector_type(4))) short bf16x4;
typedef __attribute__((ext_vector_type(4))) float f32x4;

static __device__ __forceinline__ unsigned short f2bf(float f) {
    unsigned u = __float_as_uint(f);
    unsigned r = (u + 0x7fffu + ((u >> 16) & 1u)) >> 16;
    return (unsigned short)r;
}
static __device__ __forceinline__ float bfhi2f(unsigned u) { return __uint_as_float(u & 0xffff0000u); }
static __device__ __forceinline__ float bflo2f(unsigned u) { return __uint_as_float(u << 16); }

static __device__ __forceinline__ bf16x8 load_a8(const float* p, bool ok) {
    bf16x8 a = {};
    if (ok) {
        const float4 v0 = *(const float4*)(p);
        const float4 v1 = *(const float4*)(p + 4);
        a[0] = (short)f2bf(v0.x); a[1] = (short)f2bf(v0.y);
        a[2] = (short)f2bf(v0.z); a[3] = (short)f2bf(v0.w);
        a[4] = (short)f2bf(v1.x); a[5] = (short)f2bf(v1.y);
        a[6] = (short)f2bf(v1.z); a[7] = (short)f2bf(v1.w);
    }
    return a;
}
static __device__ __forceinline__ bf16x4 pack4(float4 a) {
    bf16x4 v;
    v[0]=(short)f2bf(a.x); v[1]=(short)f2bf(a.y); v[2]=(short)f2bf(a.z); v[3]=(short)f2bf(a.w);
    return v;
}
static __device__ __forceinline__ bf16x8 pack8(float4 a, float4 b) {
    bf16x8 v;
    v[0]=(short)f2bf(a.x); v[1]=(short)f2bf(a.y); v[2]=(short)f2bf(a.z); v[3]=(short)f2bf(a.w);
    v[4]=(short)f2bf(b.x); v[5]=(short)f2bf(b.y); v[6]=(short)f2bf(b.z); v[7]=(short)f2bf(b.w);
    return v;
}

// Fragment-major tables: col = nt*16 + q*4 + j stored at idx = q*32 + nt*4 + j.

// ---- pack fp32 W[K][128] into bf16 MFMA frag order ----
__global__ void __launch_bounds__(256) k_packW(const float* __restrict__ W,
        unsigned short* __restrict__ out, int K)
{
    const int tid = blockIdx.x * 256 + threadIdx.x;
    const int total = (K / 32) * 512;
    if (tid >= total) return;
    const int lane = tid & 63, nt = (tid >> 6) & 7, kb = tid >> 9;
    const int k0 = kb * 32 + (lane >> 4) * 8;
    const int col = nt * 16 + (lane & 15);
    bf16x8 v;
    #pragma unroll
    for (int j = 0; j < 8; ++j)
        v[j] = (short)f2bf(W[(size_t)(k0 + j) * HD + col]);
    *(bf16x8*)(out + (size_t)tid * 8) = v;
}

// ---- fold: Wf = edgeW@W [32][128], bf = edgeb@W [128] ----
__global__ void __launch_bounds__(256) k_foldW(const float* __restrict__ edgeW,
        const float* __restrict__ edgeb, const float* __restrict__ W,
        float* __restrict__ Wf, float* __restrict__ bf)
{
    const int tid = blockIdx.x * 256 + threadIdx.x;
    if (tid < 4096) {
        const int k = tid >> 7, c = tid & 127;
        float s = 0.f;
        for (int j = 0; j < 128; ++j) s += edgeW[k * HD + j] * W[(size_t)j * HD + c];
        Wf[tid] = s;
    } else if (tid < 4224) {
        const int c = tid - 4096;
        float s = 0.f;
        for (int j = 0; j < 128; ++j) s += edgeb[j] * W[(size_t)j * HD + c];
        bf[c] = s;
    }
}

// ---- transposed MFMA GEMM (fp32 natural-order output) ----
template<int KB>
__global__ void __launch_bounds__(256) k_gemm_T(const float* A,
        const unsigned short* __restrict__ Wpk, const float* __restrict__ bias,
        float* C, int M)
{
    const int t = threadIdx.x, w = t >> 6, l = t & 63;
    const int n = blockIdx.x * 64 + w * 16 + (l & 15);
    const bool ok = n < M;
    const int q = l >> 4;
    const int K = KB * 32;
    f32x4 acc[8] = {};
    #pragma unroll
    for (int kb = 0; kb < KB; ++kb) {
        const bf16x8 b = load_a8(A + (size_t)n * K + kb * 32 + q * 8, ok);
        #pragma unroll
        for (int nt = 0; nt < 8; ++nt) {
            const bf16x8 aW = *(const bf16x8*)(Wpk + (((size_t)(kb * 8 + nt) * 64 + l) << 3));
            acc[nt] = __builtin_amdgcn_mfma_f32_16x16x32_bf16(aW, b, acc[nt], 0, 0, 0);
        }
    }
    if (ok) {
        float* pc = C + (size_t)n * HD + q * 4;
        #pragma unroll
        for (int nt = 0; nt < 8; ++nt) {
            const int col = nt * 16 + q * 4;
            float4 bv = bias ? *(const float4*)(bias + col) : make_float4(0.f,0.f,0.f,0.f);
            float4 o;
            o.x = acc[nt][0] + bv.x; o.y = acc[nt][1] + bv.y;
            o.z = acc[nt][2] + bv.z; o.w = acc[nt][3] + bv.w;
            *(float4*)(pc + nt * 16) = o;
        }
    }
}

// ---- transposed dual GEMM, bf16 FRAGMENT-MAJOR outputs ----
template<int KB>
__global__ void __launch_bounds__(256) k_gemm2_Tb(const float* A,
        const unsigned short* __restrict__ W0, const unsigned short* __restrict__ W1,
        const float* __restrict__ b0, unsigned short* C0, unsigned short* C1, int M)
{
    const int t = threadIdx.x, w = t >> 6, l = t & 63;
    const int n = blockIdx.x * 64 + w * 16 + (l & 15);
    const bool ok = n < M;
    const int q = l >> 4;
    const int K = KB * 32;
    f32x4 a0[8] = {}, a1[8] = {};
    #pragma unroll
    for (int kb = 0; kb < KB; ++kb) {
        const bf16x8 b = load_a8(A + (size_t)n * K + kb * 32 + q * 8, ok);
        #pragma unroll
        for (int nt = 0; nt < 8; ++nt) {
            const bf16x8 u = *(const bf16x8*)(W0 + (((size_t)(kb * 8 + nt) * 64 + l) << 3));
            const bf16x8 v = *(const bf16x8*)(W1 + (((size_t)(kb * 8 + nt) * 64 + l) << 3));
            a0[nt] = __builtin_amdgcn_mfma_f32_16x16x32_bf16(u, b, a0[nt], 0, 0, 0);
            a1[nt] = __builtin_amdgcn_mfma_f32_16x16x32_bf16(v, b, a1[nt], 0, 0, 0);
        }
    }
    if (ok) {
        unsigned short* p0 = C0 + (size_t)n * HD + q * 32;
        unsigned short* p1 = C1 + (size_t)n * HD + q * 32;
        #pragma unroll
        for (int k = 0; k < 4; ++k) {
            const int ntA = 2 * k, ntB = 2 * k + 1;
            float4 bA = b0 ? *(const float4*)(b0 + ntA * 16 + q * 4) : make_float4(0.f,0.f,0.f,0.f);
            float4 bB = b0 ? *(const float4*)(b0 + ntB * 16 + q * 4) : make_float4(0.f,0.f,0.f,0.f);
            float4 oA, oB;
            oA.x = a0[ntA][0]+bA.x; oA.y = a0[ntA][1]+bA.y; oA.z = a0[ntA][2]+bA.z; oA.w = a0[ntA][3]+bA.w;
            oB.x = a0[ntB][0]+bB.x; oB.y = a0[ntB][1]+bB.y; oB.z = a0[ntB][2]+bB.z; oB.w = a0[ntB][3]+bB.w;
            *(bf16x8*)(p0 + k * 8) = pack8(oA, oB);
            float4 uA = make_float4(a1[ntA][0], a1[ntA][1], a1[ntA][2], a1[ntA][3]);
            float4 uB = make_float4(a1[ntB][0], a1[ntB][1], a1[ntB][2], a1[ntB][3]);
            *(bf16x8*)(p1 + k * 8) = pack8(uA, uB);
        }
    }
}

// ---- degree count ----
__global__ void __launch_bounds__(256) k_count(const int* __restrict__ d, int* __restrict__ cnt, int E)
{
    const int e = blockIdx.x * 256 + threadIdx.x;
    if (e < E) atomicAdd(&cnt[d[e]], 1);
}

// ---- mean(log(cnt+1)) numerator ----
__global__ void __launch_bounds__(256) k_avglog(const int* __restrict__ cnt, float* __restrict__ stats)
{
    float s = 0.f;
    for (int n = blockIdx.x * 256 + threadIdx.x; n < NN; n += gridDim.x * 256)
        s += logf((float)cnt[n] + 1.f);
    #pragma unroll
    for (int off = 32; off > 0; off >>= 1) s += __shfl_down(s, off);
    __shared__ float ls[4];
    if ((threadIdx.x & 63) == 0) ls[threadIdx.x >> 6] = s;
    __syncthreads();
    if (threadIdx.x == 0) unsafeAtomicAdd(stats, ls[0] + ls[1] + ls[2] + ls[3]);
}

// ---- CSR build ----
__global__ void __launch_bounds__(256) k_scan_block(const int* __restrict__ cnt,
        int* __restrict__ incl, int* __restrict__ part)
{
    __shared__ int s[256];
    const int t = threadIdx.x;
    const int i = blockIdx.x * 256 + t;
    const int v = (i < NN) ? cnt[i] : 0;
    s[t] = v;
    __syncthreads();
    #pragma unroll
    for (int off = 1; off < 256; off <<= 1) {
        const int x = (t >= off) ? s[t - off] : 0;
        __syncthreads();
        s[t] += x;
        __syncthreads();
    }
    if (i < NN) incl[i] = s[t];
    if (t == 255) part[blockIdx.x] = s[255];
}

__global__ void __launch_bounds__(256) k_scan_part(const int* __restrict__ part,
        int* __restrict__ poff, int np)
{
    __shared__ int s[256];
    const int t = threadIdx.x;
    const int v = (t < np) ? part[t] : 0;
    s[t] = v;
    __syncthreads();
    #pragma unroll
    for (int off = 1; off < 256; off <<= 1) {
        const int x = (t >= off) ? s[t - off] : 0;
        __syncthreads();
        s[t] += x;
        __syncthreads();
    }
    poff[t] = s[t] - v;
}

__global__ void __launch_bounds__(256) k_scan_add(const int* __restrict__ incl,
        const int* __restrict__ cnt, const int* __restrict__ poff,
        int* __restrict__ row_start, int* __restrict__ cursor)
{
    const int i = blockIdx.x * 256 + threadIdx.x;
    if (i < NN) {
        const int excl = incl[i] - cnt[i] + poff[blockIdx.x];
        row_start[i] = excl;
        cursor[i] = excl;
    }
    if (i == 0) row_start[NN] = NE;
}

__global__ void __launch_bounds__(256) k_scatter(const int* __restrict__ dstp,
        int* cursor, int* __restrict__ sppos)
{
    const int e = blockIdx.x * 256 + threadIdx.x;
    if (e < NE) sppos[e] = atomicAdd(&cursor[dstp[e]], 1);
}

// ---- transposed msg: m' = EA@W (+bias) + xs[src]; fragment-major bf16 mbuf ----
template<int KB>
__global__ void __launch_bounds__(256) k_msg_T(const float* __restrict__ EA,
        const unsigned short* __restrict__ Wpk, const float* __restrict__ bias,
        const unsigned short* __restrict__ xsb, const int* __restrict__ srcp,
        const int* __restrict__ sppos, unsigned short* __restrict__ mbuf)
{
    const int t = threadIdx.x, w = t >> 6, l = t & 63;
    const int e = blockIdx.x * 64 + w * 16 + (l & 15);
    const int q = l >> 4;
    f32x4 acc[8] = {};
    #pragma unroll
    for (int kb = 0; kb < KB; ++kb) {
        const bf16x8 bea = load_a8(EA + (size_t)e * (KB * 32) + kb * 32 + q * 8, true);
        #pragma unroll
        for (int nt = 0; nt < 8; ++nt) {
            const bf16x8 aW = *(const bf16x8*)(Wpk + (((size_t)(kb * 8 + nt) * 64 + l) << 3));
            acc[nt] = __builtin_amdgcn_mfma_f32_16x16x32_bf16(aW, bea, acc[nt], 0, 0, 0);
        }
    }
    const int sn = srcp[e], sp = sppos[e];
    const unsigned short* ps = xsb + (size_t)sn * HD + q * 32;
    unsigned short* pm = mbuf + (size_t)sp * HD + q * 32;
    #pragma unroll
    for (int k = 0; k < 4; ++k) {
        const int ntA = 2 * k, ntB = 2 * k + 1;
        const uint4 su = *(const uint4*)(ps + k * 8);
        float4 oA, oB;
        oA.x = acc[ntA][0] + bflo2f(su.x); oA.y = acc[ntA][1] + bfhi2f(su.x);
        oA.z = acc[ntA][2] + bflo2f(su.y); oA.w = acc[ntA][3] + bfhi2f(su.y);
        oB.x = acc[ntB][0] + bflo2f(su.z); oB.y = acc[ntB][1] + bfhi2f(su.z);
        oB.z = acc[ntB][2] + bflo2f(su.w); oB.w = acc[ntB][3] + bfhi2f(su.w);
        if (bias) {
            const float4 bA = *(const float4*)(bias + ntA * 16 + q * 4);
            const float4 bB = *(const float4*)(bias + ntB * 16 + q * 4);
            oA.x += bA.x; oA.y += bA.y; oA.z += bA.z; oA.w += bA.w;
            oB.x += bB.x; oB.y += bB.y; oB.z += bB.z; oB.w += bB.w;
        }
        *(bf16x8*)(pm + k * 8) = pack8(oA, oB);
    }
}

// ---- CSR aggregation; fragment-major mbuf/xdb inputs; natural-order agg3 output ----
__global__ void __launch_bounds__(256) k_agg(const unsigned short* __restrict__ mbuf,
        const int* __restrict__ rs, const unsigned short* __restrict__ xdb,
        const float* __restrict__ stats, unsigned short* __restrict__ aggb)
{
    const int n = blockIdx.x * 4 + (threadIdx.x >> 6);
    if (n >= NN) return;
    const int lane = threadIdx.x & 63;
    const int c = lane * 2;
    const int pidx = ((c & 12) << 3) + ((c >> 4) << 2) + (c & 3);
    const int s = rs[n], e = rs[n + 1];
    const unsigned xu = *(const unsigned*)(xdb + (size_t)n * HD + pidx);
    const float xv0 = bflo2f(xu), xv1 = bfhi2f(xu);
    float s0=0.f, s1=0.f, q0=0.f, q1=0.f;
    float mn0=INFINITY, mn1=INFINITY, mx0=-INFINITY, mx1=-INFINITY;
    for (int i = s; i < e; ++i) {
        const unsigned u = *(const unsigned*)(mbuf + (size_t)i * HD + pidx);
        const float v0 = bflo2f(u), v1 = bfhi2f(u);
        s0 += v0; s1 += v1;
        q0 += v0 * v0; q1 += v1 * v1;
        mn0 = fminf(mn0, v0); mn1 = fminf(mn1, v1);
        mx0 = fmaxf(mx0, v0); mx1 = fmaxf(mx1, v1);
    }
    const int deg = e - s;
    const float inv = 1.f / (float)(deg > 1 ? deg : 1);
    const float fd = (float)deg * inv;
    const float m0p = s0 * inv, m1p = s1 * inv;
    const float sd0 = sqrtf(fmaxf(q0 * inv - m0p * m0p, 0.f) + 1e-5f);
    const float sd1 = sqrtf(fmaxf(q1 * inv - m1p * m1p, 0.f) + 1e-5f);
    const bool has = deg > 0;
    const float v0[4] = { m0p + fd * xv0, has ? mn0 + xv0 : 0.f,
                          has ? mx0 + xv0 : 0.f, sd0 };
    const float v1[4] = { m1p + fd * xv1, has ? mn1 + xv1 : 0.f,
                          has ? mx1 + xv1 : 0.f, sd1 };
    const float avg = stats[0] * (1.f / (float)NN);
    const float lg = logf(fmaxf((float)deg, 1.f) + 1.f);
    const float amp = lg / avg, att = avg / lg;
    unsigned* a = (unsigned*)(aggb + (size_t)n * 1536 + c);
    #pragma unroll
    for (int sct = 0; sct < 4; ++sct) {
        a[sct * 64]       = (unsigned)f2bf(v0[sct])       | ((unsigned)f2bf(v1[sct]) << 16);
        a[256 + sct * 64] = (unsigned)f2bf(v0[sct] * amp) | ((unsigned)f2bf(v1[sct] * amp) << 16);
        a[512 + sct * 64] = (unsigned)f2bf(v0[sct] * att) | ((unsigned)f2bf(v1[sct] * att) << 16);
    }
}

// ---- transposed post+lin ----
__global__ void __launch_bounds__(256) k_post_lin_T(const float* __restrict__ x,
        const unsigned short* __restrict__ aggb, const unsigned short* __restrict__ PWpk,
        const float* __restrict__ pb, const unsigned short* __restrict__ LNpk,
        const float* __restrict__ lb, float* __restrict__ outb, int M)
{
    __shared__ unsigned short s_o16[64 * 128];
    const int t = threadIdx.x, w = t >> 6, l = t & 63;
    const int el = w * 16 + (l & 15);
    const int n = blockIdx.x * 64 + el;
    const bool ok = n < M;
    const int q = l >> 4;
    f32x4 acc[8] = {};
    #pragma unroll
    for (int kb = 0; kb < 4; ++kb) {
        const bf16x8 b = load_a8(x + (size_t)n * HD + kb * 32 + q * 8, ok);
        #pragma unroll
        for (int nt = 0; nt < 8; ++nt) {
            const bf16x8 aW = *(const bf16x8*)(PWpk + (((size_t)(kb * 8 + nt) * 64 + l) << 3));
            acc[nt] = __builtin_amdgcn_mfma_f32_16x16x32_bf16(aW, b, acc[nt], 0, 0, 0);
        }
    }
    const unsigned short* arow = aggb + (size_t)n * 1536 + q * 8;
    #pragma unroll 4
    for (int kb = 4; kb < 52; ++kb) {
        bf16x8 b = {};
        if (ok) b = *(const bf16x8*)(arow + (size_t)(kb - 4) * 32);
        #pragma unroll
        for (int nt = 0; nt < 8; ++nt) {
            const bf16x8 aW = *(const bf16x8*)(PWpk + (((size_t)(kb * 8 + nt) * 64 + l) << 3));
            acc[nt] = __builtin_amdgcn_mfma_f32_16x16x32_bf16(aW, b, acc[nt], 0, 0, 0);
        }
    }
    #pragma unroll
    for (int nt = 0; nt < 8; ++nt) {
        const int col = nt * 16 + q * 4;
        const float4 bv = *(const float4*)(pb + col);
        float4 o;
        o.x = acc[nt][0] + bv.x; o.y = acc[nt][1] + bv.y;
        o.z = acc[nt][2] + bv.z; o.w = acc[nt][3] + bv.w;
        const int bcol = nt * 32 + q * 8;
        const int slot = bcol >> 4;
        const int ba = el * 256 + ((slot ^ (el & 7)) << 4) + (bcol & 15);
        *(bf16x4*)((char*)s_o16 + ba) = pack4(o);
    }
    __syncthreads();
    f32x4 acc2[8] = {};
    #pragma unroll
    for (int kb = 0; kb < 4; ++kb) {
        const int slot = kb * 4 + q;
        const int ba = el * 256 + ((slot ^ (el & 7)) << 4);
        const bf16x8 bh = *(const bf16x8*)((const char*)s_o16 + ba);
        #pragma unroll
        for (int nt = 0; nt < 8; ++nt) {
            const bf16x8 aW = *(const bf16x8*)(LNpk + (((size_t)(kb * 8 + nt) * 64 + l) << 3));
            acc2[nt] = __builtin_amdgcn_mfma_f32_16x16x32_bf16(aW, bh, acc2[nt], 0, 0, 0);
        }
    }
    if (ok) {
        float* pc = outb + (size_t)n * HD + q * 4;
        #pragma unroll
        for (int nt = 0; nt < 8; ++nt) {
            const int col = nt * 16 + q * 4;
            const float4 bv = *(const float4*)(lb + col);
            float4 o;
            o.x = acc2[nt][0] + bv.x; o.y = acc2[nt][1] + bv.y;
            o.z = acc2[nt][2] + bv.z; o.w = acc2[nt][3] + bv.w;
            *(float4*)(pc + nt * 16) = o;
        }
    }
}

// ---- BN column sums ----
__global__ void __launch_bounds__(256) k_bnstats(const float* __restrict__ ob,
        float* __restrict__ bs, float* __restrict__ bq, int M)
{
    const int c = threadIdx.x & 127;
    const int gsub = threadIdx.x >> 7;
    float s = 0.f, qq = 0.f;
    for (int rr = blockIdx.x * 2 + gsub; rr < M; rr += gridDim.x * 2) {
        const float v = ob[(size_t)rr * HD + c];
        s += v; qq += v * v;
    }
    __shared__ float ls[2][HD], lq[2][HD];
    ls[gsub][c] = s; lq[gsub][c] = qq;
    __syncthreads();
    if (gsub == 0) {
        unsafeAtomicAdd(&bs[c], ls[0][c] + ls[1][c]);
        unsafeAtomicAdd(&bq[c], lq[0][c] + lq[1][c]);
    }
}

// ---- x = (x + relu(bn(out)))/2 ----
__global__ void __launch_bounds__(256) k_xupdate(float* x, const float* __restrict__ ob,
        const float* __restrict__ bs, const float* __restrict__ bq,
        const float* __restrict__ g, const float* __restrict__ bb)
{
    const int i = blockIdx.x * 256 + threadIdx.x;
    const int c0 = (i & 31) * 4;
    const float4 ov = ((const float4*)ob)[i];
    const float4 xv = ((const float4*)x)[i];
    const float o[4]  = {ov.x, ov.y, ov.z, ov.w};
    const float xo[4] = {xv.x, xv.y, xv.z, xv.w};
    float res[4];
    #pragma unroll
    for (int j = 0; j < 4; ++j) {
        const int c = c0 + j;
        const float mu  = bs[c] * (1.f / (float)NN);
        const float var = bq[c] * (1.f / (float)NN) - mu * mu;
        const float bn  = g[c] * (o[j] - mu) * rsqrtf(var + 1e-5f) + bb[c];
        res[j] = (xo[j] + fmaxf(bn, 0.f)) * 0.5f;
    }
    ((float4*)x)[i] = make_float4(res[0], res[1], res[2], res[3]);
}

// ---- layer-0 edge update (folded): reads eatr (K=32), computes ea0 + hid in-reg,
//      GEMM2 via LDS, writes ea1 fp32. The NE-sized ea0 embed pass is eliminated. ----
__global__ void __launch_bounds__(256) k_edge_upd0_T(const float* __restrict__ eatr,
        float* __restrict__ ea,
        const unsigned short* __restrict__ edgepk, const float* __restrict__ edgeb,
        const unsigned short* __restrict__ Wf1pk, const float* __restrict__ bf1,
        const unsigned short* __restrict__ e2pk, const float* __restrict__ e2b,
        const unsigned short* __restrict__ xs1b, const unsigned short* __restrict__ xd1b,
        const int* __restrict__ srcp, const int* __restrict__ dstp)
{
    __shared__ unsigned short s_hid[64 * 128];
    __shared__ float s_b2[128];
    const int t = threadIdx.x, w = t >> 6, l = t & 63;
    if (t < 128) s_b2[t] = e2b[t];
    const int el = w * 16 + (l & 15);
    const int e = blockIdx.x * 64 + el;
    const int q = l >> 4;
    const int sn = srcp[e], dn = dstp[e];
    // single K=32 fragment of eatr feeds both folded GEMMs
    const bf16x8 bet = load_a8(eatr + (size_t)e * EDIM + q * 8, true);
    f32x4 ea0[8] = {}, hp[8] = {};
    #pragma unroll
    for (int nt = 0; nt < 8; ++nt) {
        const bf16x8 aE = *(const bf16x8*)(edgepk + (((size_t)nt * 64 + l) << 3));
        const bf16x8 aF = *(const bf16x8*)(Wf1pk + (((size_t)nt * 64 + l) << 3));
        ea0[nt] = __builtin_amdgcn_mfma_f32_16x16x32_bf16(aE, bet, ea0[nt], 0, 0, 0);
        hp[nt]  = __builtin_amdgcn_mfma_f32_16x16x32_bf16(aF, bet, hp[nt], 0, 0, 0);
    }
    // epilogue1: hid = relu(hp + bf1 + xs1[src] + xd1[dst]) -> swizzled LDS
    {
        const unsigned short* ps = xs1b + (size_t)sn * HD + q * 32;
        const unsigned short* pd = xd1b + (size_t)dn * HD + q * 32;
        #pragma unroll
        for (int k = 0; k < 4; ++k) {
            const int ntA = 2 * k, ntB = 2 * k + 1;
            const uint4 su = *(const uint4*)(ps + k * 8);
            const uint4 du = *(const uint4*)(pd + k * 8);
            const float4 bA = *(const float4*)(bf1 + ntA * 16 + q * 4);
            const float4 bB = *(const float4*)(bf1 + ntB * 16 + q * 4);
            float4 hA, hB;
            hA.x = fmaxf(hp[ntA][0] + bA.x + bflo2f(su.x) + bflo2f(du.x), 0.f);
            hA.y = fmaxf(hp[ntA][1] + bA.y + bfhi2f(su.x) + bfhi2f(du.x), 0.f);
            hA.z = fmaxf(hp[ntA][2] + bA.z + bflo2f(su.y) + bflo2f(du.y), 0.f);
            hA.w = fmaxf(hp[ntA][3] + bA.w + bfhi2f(su.y) + bfhi2f(du.y), 0.f);
            hB.x = fmaxf(hp[ntB][0] + bB.x + bflo2f(su.z) + bflo2f(du.z), 0.f);
            hB.y = fmaxf(hp[ntB][1] + bB.y + bfhi2f(su.z) + bfhi2f(du.z), 0.f);
            hB.z = fmaxf(hp[ntB][2] + bB.z + bflo2f(su.w) + bflo2f(du.w), 0.f);
            hB.w = fmaxf(hp[ntB][3] + bB.w + bfhi2f(su.w) + bfhi2f(du.w), 0.f);
            const int bcolA = ntA * 32 + q * 8;
            const int baA = el * 256 + (((bcolA >> 4) ^ (el & 7)) << 4) + (bcolA & 15);
            *(bf16x4*)((char*)s_hid + baA) = pack4(hA);
            const int bcolB = ntB * 32 + q * 8;
            const int baB = el * 256 + (((bcolB >> 4) ^ (el & 7)) << 4) + (bcolB & 15);
            *(bf16x4*)((char*)s_hid + baB) = pack4(hB);
        }
    }
    __syncthreads();
    // GEMM2: em2^T @ hid^T (K=128 from LDS)
    f32x4 acc2[8] = {};
    #pragma unroll
    for (int kb = 0; kb < 4; ++kb) {
        const int slot = kb * 4 + q;
        const int ba = el * 256 + ((slot ^ (el & 7)) << 4);
        const bf16x8 bh = *(const bf16x8*)((const char*)s_hid + ba);
        #pragma unroll
        for (int nt = 0; nt < 8; ++nt) {
            const bf16x8 aW = *(const bf16x8*)(e2pk + (((size_t)(kb * 8 + nt) * 64 + l) << 3));
            acc2[nt] = __builtin_amdgcn_mfma_f32_16x16x32_bf16(aW, bh, acc2[nt], 0, 0, 0);
        }
    }
    // epilogue2: ea1 = (ea0 + edgeb) + (acc2 + e2b)/2; fp32 stores
    {
        float* pe = ea + (size_t)e * HD + q * 4;
        #pragma unroll
        for (int nt = 0; nt < 8; ++nt) {
            const int col = nt * 16 + q * 4;
            const float4 eb = *(const float4*)(edgeb + col);
            const float4 bv = *(const float4*)(&s_b2[col]);
            float4 o;
            o.x = ea0[nt][0] + eb.x + (acc2[nt][0] + bv.x) * 0.5f;
            o.y = ea0[nt][1] + eb.y + (acc2[nt][1] + bv.y) * 0.5f;
            o.z = ea0[nt][2] + eb.z + (acc2[nt][2] + bv.z) * 0.5f;
            o.w = ea0[nt][3] + eb.w + (acc2[nt][3] + bv.w) * 0.5f;
            *(float4*)(pe + nt * 16) = o;
        }
    }
}

// ---- transposed edge update (layer 1, standalone) ----
__global__ void __launch_bounds__(256) k_edge_upd_T(float* ea,
        const unsigned short* __restrict__ W1epk, const unsigned short* __restrict__ e2pk,
        const float* __restrict__ e2b, const unsigned short* __restrict__ xs1b,
        const unsigned short* __restrict__ xd1b, const int* __restrict__ srcp,
        const int* __restrict__ dstp)
{
    __shared__ unsigned short s_hid[64 * 128];
    __shared__ float s_b2[128];
    const int t = threadIdx.x, w = t >> 6, l = t & 63;
    const int row0b = blockIdx.x * 64;
    if (t < 128) s_b2[t] = e2b[t];
    const int el = w * 16 + (l & 15);
    const int e = row0b + el;
    const int q = l >> 4, kq = q * 8;
    f32x4 acc1[8] = {};
    #pragma unroll
    for (int kb = 0; kb < 4; ++kb) {
        const bf16x8 bea = load_a8(ea + (size_t)e * HD + kb * 32 + kq, true);
        #pragma unroll
        for (int nt = 0; nt < 8; ++nt) {
            const bf16x8 aW = *(const bf16x8*)(W1epk + (((size_t)(kb * 8 + nt) * 64 + l) << 3));
            acc1[nt] = __builtin_amdgcn_mfma_f32_16x16x32_bf16(aW, bea, acc1[nt], 0, 0, 0);
        }
    }
    {
        const int sn = srcp[e], dn = dstp[e];
        const unsigned short* ps = xs1b + (size_t)sn * HD + q * 32;
        const unsigned short* pd = xd1b + (size_t)dn * HD + q * 32;
        #pragma unroll
        for (int k = 0; k < 4; ++k) {
            const int ntA = 2 * k, ntB = 2 * k + 1;
            const uint4 su = *(const uint4*)(ps + k * 8);
            const uint4 du = *(const uint4*)(pd + k * 8);
            float4 hA, hB;
            hA.x = fmaxf(acc1[ntA][0] + bflo2f(su.x) + bflo2f(du.x), 0.f);
            hA.y = fmaxf(acc1[ntA][1] + bfhi2f(su.x) + bfhi2f(du.x), 0.f);
            hA.z = fmaxf(acc1[ntA][2] + bflo2f(su.y) + bflo2f(du.y), 0.f);
            hA.w = fmaxf(acc1[ntA][3] + bfhi2f(su.y) + bfhi2f(du.y), 0.f);
            hB.x = fmaxf(acc1[ntB][0] + bflo2f(su.z) + bflo2f(du.z), 0.f);
            hB.y = fmaxf(acc1[ntB][1] + bfhi2f(su.z) + bfhi2f(du.z), 0.f);
            hB.z = fmaxf(acc1[ntB][2] + bflo2f(su.w) + bflo2f(du.w), 0.f);
            hB.w = fmaxf(acc1[ntB][3] + bfhi2f(su.w) + bfhi2f(du.w), 0.f);
            const int bcolA = ntA * 32 + q * 8;
            const int baA = el * 256 + (((bcolA >> 4) ^ (el & 7)) << 4) + (bcolA & 15);
            *(bf16x4*)((char*)s_hid + baA) = pack4(hA);
            const int bcolB = ntB * 32 + q * 8;
            const int baB = el * 256 + (((bcolB >> 4) ^ (el & 7)) << 4) + (bcolB & 15);
            *(bf16x4*)((char*)s_hid + baB) = pack4(hB);
        }
    }
    __syncthreads();
    f32x4 acc2[8] = {};
    #pragma unroll
    for (int kb = 0; kb < 4; ++kb) {
        const int slot = kb * 4 + q;
        const int ba = el * 256 + ((slot ^ (el & 7)) << 4);
        const bf16x8 bh = *(const bf16x8*)((const char*)s_hid + ba);
        #pragma unroll
        for (int nt = 0; nt < 8; ++nt) {
            const bf16x8 aW = *(const bf16x8*)(e2pk + (((size_t)(kb * 8 + nt) * 64 + l) << 3));
            acc2[nt] = __builtin_amdgcn_mfma_f32_16x16x32_bf16(aW, bh, acc2[nt], 0, 0, 0);
        }
    }
    {
        float* pe = ea + (size_t)e * HD + q * 4;
        #pragma unroll
        for (int nt = 0; nt < 8; ++nt) {
            const float4 eo = *(const float4*)(pe + nt * 16);
            const float4 bv = *(const float4*)(&s_b2[nt * 16 + q * 4]);
            float4 o;
            o.x = eo.x + (acc2[nt][0] + bv.x) * 0.5f;
            o.y = eo.y + (acc2[nt][1] + bv.y) * 0.5f;
            o.z = eo.z + (acc2[nt][2] + bv.z) * 0.5f;
            o.w = eo.w + (acc2[nt][3] + bv.w) * 0.5f;
            *(float4*)(pe + nt * 16) = o;
        }
    }
}

extern "C" void kernel_launch(void* const* d_in, const int* in_sizes, int n_in,
                              void* d_out, int out_size, void* d_ws, size_t ws_size,
                              hipStream_t stream)
{
    const float* x0    = (const float*)d_in[0];
    const float* eatr  = (const float*)d_in[1];
    const float* teatr = (const float*)d_in[2];
    const float* nodeW = (const float*)d_in[3];
    const float* nodeb = (const float*)d_in[4];
    const float* edgeW = (const float*)d_in[5];
    const float* edgeb = (const float*)d_in[6];
    const float* preW  = (const float*)d_in[7];
    const float* preb  = (const float*)d_in[8];
    const float* postW = (const float*)d_in[9];
    const float* postb = (const float*)d_in[10];
    const float* linW  = (const float*)d_in[11];
    const float* linb  = (const float*)d_in[12];
    const float* bng   = (const float*)d_in[13];
    const float* bnb   = (const float*)d_in[14];
    const float* em1W  = (const float*)d_in[15];
    const float* em1b  = (const float*)d_in[16];
    const float* em2W  = (const float*)d_in[17];
    const float* em2b  = (const float*)d_in[18];
    const int*   eidx  = (const int*)d_in[19];
    const int* srcp = eidx;
    const int* dstp = eidx + NE;

    float* out_x  = (float*)d_out;
    float* out_ea = out_x + (size_t)NN * HD;
    float* out_te = out_ea + (size_t)NE * HD;

    const size_t NH = (size_t)NN * HD;
    const size_t EH = (size_t)NE * HD;
    unsigned short* xdb = (unsigned short*)d_ws;     // fragment-major bf16 tables
    unsigned short* xsb = xdb + NH;
    float* outb  = (float*)(xsb + NH);
    float* stats = outb + NH;
    float* Wf0   = stats + 512;        // folded edgeW@We0
    float* bf0   = Wf0 + 4096;
    float* Wf1   = bf0 + 128;          // folded edgeW@W1e0
    float* bf1   = Wf1 + 4096;
    int*   cnt      = (int*)(bf1 + 128);
    int*   row_start = cnt + NN;
    int*   cursor   = row_start + NN + 1;
    int*   tmpincl  = cursor + NN;
    int*   part     = tmpincl + NN;
    int*   poff     = part + 256;
    int*   sppos    = poff + 256;
    unsigned short* mbuf = (unsigned short*)(((uintptr_t)(sppos + NE) + 15) & ~(uintptr_t)15);
    unsigned short* aggb = mbuf + EH;
    unsigned short* pk   = aggb + (size_t)NN * 1536;
    const size_t KBSZ = 512 * 8;
    unsigned short* pkPost = pk;                       // 104 kbs
    unsigned short* pkPre  = pkPost + 104 * KBSZ;      // 24 kbs
    unsigned short* pkEm1  = pkPre  + 24 * KBSZ;       // 24 kbs
    unsigned short* pkLin  = pkEm1  + 24 * KBSZ;       // 8 kbs
    unsigned short* pkEm2  = pkLin  + 8 * KBSZ;        // 8 kbs
    unsigned short* pkNode = pkEm2  + 8 * KBSZ;        // 2 kbs
    unsigned short* pkEdge = pkNode + 2 * KBSZ;        // 1 kb
    unsigned short* pkWe0f = pkEdge + 1 * KBSZ;        // 1 kb
    unsigned short* pkWf1  = pkWe0f + 1 * KBSZ;        // 1 kb

    hipMemsetAsync(cnt, 0, NN * sizeof(int), stream);
    hipMemsetAsync(stats, 0, 512 * sizeof(float), stream);

    k_packW<<<208, 256, 0, stream>>>(postW, pkPost, 3328);
    k_packW<<<48, 256, 0, stream>>>(preW,  pkPre,  768);
    k_packW<<<48, 256, 0, stream>>>(em1W,  pkEm1,  768);
    k_packW<<<16, 256, 0, stream>>>(linW,  pkLin,  256);
    k_packW<<<16, 256, 0, stream>>>(em2W,  pkEm2,  256);
    k_packW<<<4, 256, 0, stream>>>(nodeW, pkNode, 64);
    k_packW<<<2, 256, 0, stream>>>(edgeW, pkEdge, 32);
    k_foldW<<<17, 256, 0, stream>>>(edgeW, edgeb, preW + 256 * HD, Wf0, bf0);   // msg(0)
    k_foldW<<<17, 256, 0, stream>>>(edgeW, edgeb, em1W + 256 * HD, Wf1, bf1);   // edge_upd(0) GEMM1
    k_packW<<<2, 256, 0, stream>>>(Wf0, pkWe0f, 32);
    k_packW<<<2, 256, 0, stream>>>(Wf1, pkWf1, 32);

    // prologue: only teatr + node embeds (NE-sized ea0 embed eliminated)
    k_gemm_T<1><<<(NTE + 63) / 64, 256, 0, stream>>>(teatr, pkEdge, edgeb, out_te, NTE);
    k_gemm_T<2><<<(NN + 63) / 64, 256, 0, stream>>>(x0, pkNode, nodeb, out_x, NN);

    k_count<<<(NE + 255) / 256, 256, 0, stream>>>(dstp, cnt, NE);
    k_avglog<<<256, 256, 0, stream>>>(cnt, stats);
    k_scan_block<<<SCAN_B, 256, 0, stream>>>(cnt, tmpincl, part);
    k_scan_part<<<1, 256, 0, stream>>>(part, poff, SCAN_B);
    k_scan_add<<<SCAN_B, 256, 0, stream>>>(tmpincl, cnt, poff, row_start, cursor);
    k_scatter<<<(NE + 255) / 256, 256, 0, stream>>>(dstp, cursor, sppos);

    const int gn = (NN + 63) / 64;
    const int ge = NE / 64;

    for (int l = 0; l < NL; ++l) {
        const unsigned short* Wd_pk  = pkPre + (size_t)(l * 12 + 0) * KBSZ;
        const unsigned short* Ws_pk  = pkPre + (size_t)(l * 12 + 4) * KBSZ;
        const unsigned short* We_pk  = pkPre + (size_t)(l * 12 + 8) * KBSZ;
        const unsigned short* W1s_pk = pkEm1 + (size_t)(l * 12 + 0) * KBSZ;
        const unsigned short* W1d_pk = pkEm1 + (size_t)(l * 12 + 4) * KBSZ;
        const unsigned short* W1e_pk = pkEm1 + (size_t)(l * 12 + 8) * KBSZ;
        const unsigned short* PW_pk  = pkPost + (size_t)l * 52 * KBSZ;
        const unsigned short* lin_pk = pkLin + (size_t)l * 4 * KBSZ;
        const unsigned short* em2_pk = pkEm2 + (size_t)l * 4 * KBSZ;
        const float* pbl = preb + l * HD;
        const float* pob = postb + l * HD;
        const float* lb  = linb + l * HD;
        const float* g_  = bng + l * HD;
        const float* b_  = bnb + l * HD;
        const float* e1b = em1b + l * HD;
        const float* e2b = em2b + l * HD;

        hipMemsetAsync(stats + 128, 0, 256 * sizeof(float), stream);

        k_gemm2_Tb<4><<<gn, 256, 0, stream>>>(out_x, Wd_pk, Ws_pk, pbl, xdb, xsb, NN);
        if (l == 0)
            k_msg_T<1><<<ge, 256, 0, stream>>>(eatr, pkWe0f, bf0, xsb, srcp, sppos, mbuf);
        else
            k_msg_T<4><<<ge, 256, 0, stream>>>(out_ea, We_pk, nullptr, xsb, srcp, sppos, mbuf);
        k_agg<<<(NN + 3) / 4, 256, 0, stream>>>(mbuf, row_start, xdb, stats, aggb);
        k_post_lin_T<<<gn, 256, 0, stream>>>(out_x, aggb, PW_pk, pob, lin_pk, lb, outb, NN);
        k_bnstats<<<256, 256, 0, stream>>>(outb, stats + 128, stats + 256, NN);
        k_xupdate<<<NN * 32 / 256, 256, 0, stream>>>(out_x, outb, stats + 128, stats + 256, g_, b_);
        k_gemm2_Tb<4><<<gn, 256, 0, stream>>>(out_x, W1d_pk, W1s_pk, e1b, xdb, xsb, NN);
        if (l == 0)
            k_edge_upd0_T<<<ge, 256, 0, stream>>>(eatr, out_ea, pkEdge, edgeb,
                                                  pkWf1, bf1, em2_pk, e2b, xsb, xdb, srcp, dstp);
        else
            k_edge_upd_T<<<ge, 256, 0, stream>>>(out_ea, W1e_pk, em2_pk, e2b, xsb, xdb, srcp, dstp);
    }
}

// Round 12
// 1223.598 us; speedup vs baseline: 1.1961x; 1.0901x over previous
//
#include <hip/hip_runtime.h>
#include <math.h>

#define NN  50000
#define NE  400000
#define NTE 50000
#define FIN 64
#define EDIM 32
#define HD  128
#define NL  2
#define SCAN_B ((NN + 255) / 256)

typedef __attribute__((ext_vector_type(8))) short bf16x8;
typedef __attribute__((ext_vector_type(4))) short bf16x4;
typedef __attribute__((ext_vector_type(4))) float f32x4;

static __device__ __forceinline__ unsigned short f2bf(float f) {
    unsigned u = __float_as_uint(f);
    unsigned r = (u + 0x7fffu + ((u >> 16) & 1u)) >> 16;
    return (unsigned short)r;
}
static __device__ __forceinline__ float bfhi2f(unsigned u) { return __uint_as_float(u & 0xffff0000u); }
static __device__ __forceinline__ float bflo2f(unsigned u) { return __uint_as_float(u << 16); }

static __device__ __forceinline__ bf16x8 load_a8(const float* p, bool ok) {
    bf16x8 a = {};
    if (ok) {
        const float4 v0 = *(const float4*)(p);
        const float4 v1 = *(const float4*)(p + 4);
        a[0] = (short)f2bf(v0.x); a[1] = (short)f2bf(v0.y);
        a[2] = (short)f2bf(v0.z); a[3] = (short)f2bf(v0.w);
        a[4] = (short)f2bf(v1.x); a[5] = (short)f2bf(v1.y);
        a[6] = (short)f2bf(v1.z); a[7] = (short)f2bf(v1.w);
    }
    return a;
}
static __device__ __forceinline__ bf16x4 pack4(float4 a) {
    bf16x4 v;
    v[0]=(short)f2bf(a.x); v[1]=(short)f2bf(a.y); v[2]=(short)f2bf(a.z); v[3]=(short)f2bf(a.w);
    return v;
}
static __device__ __forceinline__ bf16x8 pack8(float4 a, float4 b) {
    bf16x8 v;
    v[0]=(short)f2bf(a.x); v[1]=(short)f2bf(a.y); v[2]=(short)f2bf(a.z); v[3]=(short)f2bf(a.w);
    v[4]=(short)f2bf(b.x); v[5]=(short)f2bf(b.y); v[6]=(short)f2bf(b.z); v[7]=(short)f2bf(b.w);
    return v;
}

// Fragment-major tables: col = nt*16 + q*4 + j stored at idx = q*32 + nt*4 + j.

// ---- pack fp32 W[K][128] into bf16 MFMA frag order ----
__global__ void __launch_bounds__(256) k_packW(const float* __restrict__ W,
        unsigned short* __restrict__ out, int K)
{
    const int tid = blockIdx.x * 256 + threadIdx.x;
    const int total = (K / 32) * 512;
    if (tid >= total) return;
    const int lane = tid & 63, nt = (tid >> 6) & 7, kb = tid >> 9;
    const int k0 = kb * 32 + (lane >> 4) * 8;
    const int col = nt * 16 + (lane & 15);
    bf16x8 v;
    #pragma unroll
    for (int j = 0; j < 8; ++j)
        v[j] = (short)f2bf(W[(size_t)(k0 + j) * HD + col]);
    *(bf16x8*)(out + (size_t)tid * 8) = v;
}

// ---- fold: Wf = edgeW@W [32][128], bf = edgeb@W [128] ----
__global__ void __launch_bounds__(256) k_foldW(const float* __restrict__ edgeW,
        const float* __restrict__ edgeb, const float* __restrict__ W,
        float* __restrict__ Wf, float* __restrict__ bf)
{
    const int tid = blockIdx.x * 256 + threadIdx.x;
    if (tid < 4096) {
        const int k = tid >> 7, c = tid & 127;
        float s = 0.f;
        for (int j = 0; j < 128; ++j) s += edgeW[k * HD + j] * W[(size_t)j * HD + c];
        Wf[tid] = s;
    } else if (tid < 4224) {
        const int c = tid - 4096;
        float s = 0.f;
        for (int j = 0; j < 128; ++j) s += edgeb[j] * W[(size_t)j * HD + c];
        bf[c] = s;
    }
}

// ---- transposed MFMA GEMM (fp32 natural-order output) ----
template<int KB>
__global__ void __launch_bounds__(256) k_gemm_T(const float* A,
        const unsigned short* __restrict__ Wpk, const float* __restrict__ bias,
        float* C, int M)
{
    const int t = threadIdx.x, w = t >> 6, l = t & 63;
    const int n = blockIdx.x * 64 + w * 16 + (l & 15);
    const bool ok = n < M;
    const int q = l >> 4;
    const int K = KB * 32;
    f32x4 acc[8] = {};
    #pragma unroll
    for (int kb = 0; kb < KB; ++kb) {
        const bf16x8 b = load_a8(A + (size_t)n * K + kb * 32 + q * 8, ok);
        #pragma unroll
        for (int nt = 0; nt < 8; ++nt) {
            const bf16x8 aW = *(const bf16x8*)(Wpk + (((size_t)(kb * 8 + nt) * 64 + l) << 3));
            acc[nt] = __builtin_amdgcn_mfma_f32_16x16x32_bf16(aW, b, acc[nt], 0, 0, 0);
        }
    }
    if (ok) {
        float* pc = C + (size_t)n * HD + q * 4;
        #pragma unroll
        for (int nt = 0; nt < 8; ++nt) {
            const int col = nt * 16 + q * 4;
            float4 bv = bias ? *(const float4*)(bias + col) : make_float4(0.f,0.f,0.f,0.f);
            float4 o;
            o.x = acc[nt][0] + bv.x; o.y = acc[nt][1] + bv.y;
            o.z = acc[nt][2] + bv.z; o.w = acc[nt][3] + bv.w;
            *(float4*)(pc + nt * 16) = o;
        }
    }
}

// ---- transposed dual GEMM, bf16 FRAGMENT-MAJOR outputs ----
template<int KB>
__global__ void __launch_bounds__(256) k_gemm2_Tb(const float* A,
        const unsigned short* __restrict__ W0, const unsigned short* __restrict__ W1,
        const float* __restrict__ b0, unsigned short* C0, unsigned short* C1, int M)
{
    const int t = threadIdx.x, w = t >> 6, l = t & 63;
    const int n = blockIdx.x * 64 + w * 16 + (l & 15);
    const bool ok = n < M;
    const int q = l >> 4;
    const int K = KB * 32;
    f32x4 a0[8] = {}, a1[8] = {};
    #pragma unroll
    for (int kb = 0; kb < KB; ++kb) {
        const bf16x8 b = load_a8(A + (size_t)n * K + kb * 32 + q * 8, ok);
        #pragma unroll
        for (int nt = 0; nt < 8; ++nt) {
            const bf16x8 u = *(const bf16x8*)(W0 + (((size_t)(kb * 8 + nt) * 64 + l) << 3));
            const bf16x8 v = *(const bf16x8*)(W1 + (((size_t)(kb * 8 + nt) * 64 + l) << 3));
            a0[nt] = __builtin_amdgcn_mfma_f32_16x16x32_bf16(u, b, a0[nt], 0, 0, 0);
            a1[nt] = __builtin_amdgcn_mfma_f32_16x16x32_bf16(v, b, a1[nt], 0, 0, 0);
        }
    }
    if (ok) {
        unsigned short* p0 = C0 + (size_t)n * HD + q * 32;
        unsigned short* p1 = C1 + (size_t)n * HD + q * 32;
        #pragma unroll
        for (int k = 0; k < 4; ++k) {
            const int ntA = 2 * k, ntB = 2 * k + 1;
            float4 bA = b0 ? *(const float4*)(b0 + ntA * 16 + q * 4) : make_float4(0.f,0.f,0.f,0.f);
            float4 bB = b0 ? *(const float4*)(b0 + ntB * 16 + q * 4) : make_float4(0.f,0.f,0.f,0.f);
            float4 oA, oB;
            oA.x = a0[ntA][0]+bA.x; oA.y = a0[ntA][1]+bA.y; oA.z = a0[ntA][2]+bA.z; oA.w = a0[ntA][3]+bA.w;
            oB.x = a0[ntB][0]+bB.x; oB.y = a0[ntB][1]+bB.y; oB.z = a0[ntB][2]+bB.z; oB.w = a0[ntB][3]+bB.w;
            *(bf16x8*)(p0 + k * 8) = pack8(oA, oB);
            float4 uA = make_float4(a1[ntA][0], a1[ntA][1], a1[ntA][2], a1[ntA][3]);
            float4 uB = make_float4(a1[ntB][0], a1[ntB][1], a1[ntB][2], a1[ntB][3]);
            *(bf16x8*)(p1 + k * 8) = pack8(uA, uB);
        }
    }
}

// ---- degree count ----
__global__ void __launch_bounds__(256) k_count(const int* __restrict__ d, int* __restrict__ cnt, int E)
{
    const int e = blockIdx.x * 256 + threadIdx.x;
    if (e < E) atomicAdd(&cnt[d[e]], 1);
}

// ---- mean(log(cnt+1)) numerator ----
__global__ void __launch_bounds__(256) k_avglog(const int* __restrict__ cnt, float* __restrict__ stats)
{
    float s = 0.f;
    for (int n = blockIdx.x * 256 + threadIdx.x; n < NN; n += gridDim.x * 256)
        s += logf((float)cnt[n] + 1.f);
    #pragma unroll
    for (int off = 32; off > 0; off >>= 1) s += __shfl_down(s, off);
    __shared__ float ls[4];
    if ((threadIdx.x & 63) == 0) ls[threadIdx.x >> 6] = s;
    __syncthreads();
    if (threadIdx.x == 0) unsafeAtomicAdd(stats, ls[0] + ls[1] + ls[2] + ls[3]);
}

// ---- CSR build ----
__global__ void __launch_bounds__(256) k_scan_block(const int* __restrict__ cnt,
        int* __restrict__ incl, int* __restrict__ part)
{
    __shared__ int s[256];
    const int t = threadIdx.x;
    const int i = blockIdx.x * 256 + t;
    const int v = (i < NN) ? cnt[i] : 0;
    s[t] = v;
    __syncthreads();
    #pragma unroll
    for (int off = 1; off < 256; off <<= 1) {
        const int x = (t >= off) ? s[t - off] : 0;
        __syncthreads();
        s[t] += x;
        __syncthreads();
    }
    if (i < NN) incl[i] = s[t];
    if (t == 255) part[blockIdx.x] = s[255];
}

__global__ void __launch_bounds__(256) k_scan_part(const int* __restrict__ part,
        int* __restrict__ poff, int np)
{
    __shared__ int s[256];
    const int t = threadIdx.x;
    const int v = (t < np) ? part[t] : 0;
    s[t] = v;
    __syncthreads();
    #pragma unroll
    for (int off = 1; off < 256; off <<= 1) {
        const int x = (t >= off) ? s[t - off] : 0;
        __syncthreads();
        s[t] += x;
        __syncthreads();
    }
    poff[t] = s[t] - v;
}

__global__ void __launch_bounds__(256) k_scan_add(const int* __restrict__ incl,
        const int* __restrict__ cnt, const int* __restrict__ poff,
        int* __restrict__ row_start, int* __restrict__ cursor)
{
    const int i = blockIdx.x * 256 + threadIdx.x;
    if (i < NN) {
        const int excl = incl[i] - cnt[i] + poff[blockIdx.x];
        row_start[i] = excl;
        cursor[i] = excl;
    }
    if (i == 0) row_start[NN] = NE;
}

__global__ void __launch_bounds__(256) k_scatter(const int* __restrict__ dstp,
        int* cursor, int* __restrict__ sppos)
{
    const int e = blockIdx.x * 256 + threadIdx.x;
    if (e < NE) sppos[e] = atomicAdd(&cursor[dstp[e]], 1);
}

// ---- layer-0 msg (folded, eatr fp32 K=32): m' = eatr@Wf + bf + xs[src]; frag-major mbuf ----
__global__ void __launch_bounds__(256) k_msg0_T(const float* __restrict__ eatr,
        const unsigned short* __restrict__ Wpk, const float* __restrict__ bias,
        const unsigned short* __restrict__ xsb, const int* __restrict__ srcp,
        const int* __restrict__ sppos, unsigned short* __restrict__ mbuf)
{
    const int t = threadIdx.x, w = t >> 6, l = t & 63;
    const int e = blockIdx.x * 64 + w * 16 + (l & 15);
    const int q = l >> 4;
    f32x4 acc[8] = {};
    const bf16x8 bea = load_a8(eatr + (size_t)e * EDIM + q * 8, true);
    #pragma unroll
    for (int nt = 0; nt < 8; ++nt) {
        const bf16x8 aW = *(const bf16x8*)(Wpk + (((size_t)nt * 64 + l) << 3));
        acc[nt] = __builtin_amdgcn_mfma_f32_16x16x32_bf16(aW, bea, acc[nt], 0, 0, 0);
    }
    const int sn = srcp[e], sp = sppos[e];
    const unsigned short* ps = xsb + (size_t)sn * HD + q * 32;
    unsigned short* pm = mbuf + (size_t)sp * HD + q * 32;
    #pragma unroll
    for (int k = 0; k < 4; ++k) {
        const int ntA = 2 * k, ntB = 2 * k + 1;
        const uint4 su = *(const uint4*)(ps + k * 8);
        const float4 bA = *(const float4*)(bias + ntA * 16 + q * 4);
        const float4 bB = *(const float4*)(bias + ntB * 16 + q * 4);
        float4 oA, oB;
        oA.x = acc[ntA][0] + bflo2f(su.x) + bA.x; oA.y = acc[ntA][1] + bfhi2f(su.x) + bA.y;
        oA.z = acc[ntA][2] + bflo2f(su.y) + bA.z; oA.w = acc[ntA][3] + bfhi2f(su.y) + bA.w;
        oB.x = acc[ntB][0] + bflo2f(su.z) + bB.x; oB.y = acc[ntB][1] + bfhi2f(su.z) + bB.y;
        oB.z = acc[ntB][2] + bflo2f(su.w) + bB.z; oB.w = acc[ntB][3] + bfhi2f(su.w) + bB.w;
        *(bf16x8*)(pm + k * 8) = pack8(oA, oB);
    }
}

// ---- layer-1 msg (bf16 ea input): m' = eab@We + xs[src]; frag-major mbuf ----
__global__ void __launch_bounds__(256) k_msg_Tb(const unsigned short* __restrict__ eab,
        const unsigned short* __restrict__ Wpk, const unsigned short* __restrict__ xsb,
        const int* __restrict__ srcp, const int* __restrict__ sppos,
        unsigned short* __restrict__ mbuf)
{
    const int t = threadIdx.x, w = t >> 6, l = t & 63;
    const int e = blockIdx.x * 64 + w * 16 + (l & 15);
    const int q = l >> 4;
    f32x4 acc[8] = {};
    #pragma unroll
    for (int kb = 0; kb < 4; ++kb) {
        const bf16x8 bea = *(const bf16x8*)(eab + (size_t)e * HD + kb * 32 + q * 8);
        #pragma unroll
        for (int nt = 0; nt < 8; ++nt) {
            const bf16x8 aW = *(const bf16x8*)(Wpk + (((size_t)(kb * 8 + nt) * 64 + l) << 3));
            acc[nt] = __builtin_amdgcn_mfma_f32_16x16x32_bf16(aW, bea, acc[nt], 0, 0, 0);
        }
    }
    const int sn = srcp[e], sp = sppos[e];
    const unsigned short* ps = xsb + (size_t)sn * HD + q * 32;
    unsigned short* pm = mbuf + (size_t)sp * HD + q * 32;
    #pragma unroll
    for (int k = 0; k < 4; ++k) {
        const int ntA = 2 * k, ntB = 2 * k + 1;
        const uint4 su = *(const uint4*)(ps + k * 8);
        float4 oA, oB;
        oA.x = acc[ntA][0] + bflo2f(su.x); oA.y = acc[ntA][1] + bfhi2f(su.x);
        oA.z = acc[ntA][2] + bflo2f(su.y); oA.w = acc[ntA][3] + bfhi2f(su.y);
        oB.x = acc[ntB][0] + bflo2f(su.z); oB.y = acc[ntB][1] + bfhi2f(su.z);
        oB.z = acc[ntB][2] + bflo2f(su.w); oB.w = acc[ntB][3] + bfhi2f(su.w);
        *(bf16x8*)(pm + k * 8) = pack8(oA, oB);
    }
}

// ---- CSR aggregation; fragment-major mbuf/xdb inputs; natural-order agg3 output ----
__global__ void __launch_bounds__(256) k_agg(const unsigned short* __restrict__ mbuf,
        const int* __restrict__ rs, const unsigned short* __restrict__ xdb,
        const float* __restrict__ stats, unsigned short* __restrict__ aggb)
{
    const int n = blockIdx.x * 4 + (threadIdx.x >> 6);
    if (n >= NN) return;
    const int lane = threadIdx.x & 63;
    const int c = lane * 2;
    const int pidx = ((c & 12) << 3) + ((c >> 4) << 2) + (c & 3);
    const int s = rs[n], e = rs[n + 1];
    const unsigned xu = *(const unsigned*)(xdb + (size_t)n * HD + pidx);
    const float xv0 = bflo2f(xu), xv1 = bfhi2f(xu);
    float s0=0.f, s1=0.f, q0=0.f, q1=0.f;
    float mn0=INFINITY, mn1=INFINITY, mx0=-INFINITY, mx1=-INFINITY;
    for (int i = s; i < e; ++i) {
        const unsigned u = *(const unsigned*)(mbuf + (size_t)i * HD + pidx);
        const float v0 = bflo2f(u), v1 = bfhi2f(u);
        s0 += v0; s1 += v1;
        q0 += v0 * v0; q1 += v1 * v1;
        mn0 = fminf(mn0, v0); mn1 = fminf(mn1, v1);
        mx0 = fmaxf(mx0, v0); mx1 = fmaxf(mx1, v1);
    }
    const int deg = e - s;
    const float inv = 1.f / (float)(deg > 1 ? deg : 1);
    const float fd = (float)deg * inv;
    const float m0p = s0 * inv, m1p = s1 * inv;
    const float sd0 = sqrtf(fmaxf(q0 * inv - m0p * m0p, 0.f) + 1e-5f);
    const float sd1 = sqrtf(fmaxf(q1 * inv - m1p * m1p, 0.f) + 1e-5f);
    const bool has = deg > 0;
    const float v0[4] = { m0p + fd * xv0, has ? mn0 + xv0 : 0.f,
                          has ? mx0 + xv0 : 0.f, sd0 };
    const float v1[4] = { m1p + fd * xv1, has ? mn1 + xv1 : 0.f,
                          has ? mx1 + xv1 : 0.f, sd1 };
    const float avg = stats[0] * (1.f / (float)NN);
    const float lg = logf(fmaxf((float)deg, 1.f) + 1.f);
    const float amp = lg / avg, att = avg / lg;
    unsigned* a = (unsigned*)(aggb + (size_t)n * 1536 + c);
    #pragma unroll
    for (int sct = 0; sct < 4; ++sct) {
        a[sct * 64]       = (unsigned)f2bf(v0[sct])       | ((unsigned)f2bf(v1[sct]) << 16);
        a[256 + sct * 64] = (unsigned)f2bf(v0[sct] * amp) | ((unsigned)f2bf(v1[sct] * amp) << 16);
        a[512 + sct * 64] = (unsigned)f2bf(v0[sct] * att) | ((unsigned)f2bf(v1[sct] * att) << 16);
    }
}

// ---- transposed post+lin ----
__global__ void __launch_bounds__(256) k_post_lin_T(const float* __restrict__ x,
        const unsigned short* __restrict__ aggb, const unsigned short* __restrict__ PWpk,
        const float* __restrict__ pb, const unsigned short* __restrict__ LNpk,
        const float* __restrict__ lb, float* __restrict__ outb, int M)
{
    __shared__ unsigned short s_o16[64 * 128];
    const int t = threadIdx.x, w = t >> 6, l = t & 63;
    const int el = w * 16 + (l & 15);
    const int n = blockIdx.x * 64 + el;
    const bool ok = n < M;
    const int q = l >> 4;
    f32x4 acc[8] = {};
    #pragma unroll
    for (int kb = 0; kb < 4; ++kb) {
        const bf16x8 b = load_a8(x + (size_t)n * HD + kb * 32 + q * 8, ok);
        #pragma unroll
        for (int nt = 0; nt < 8; ++nt) {
            const bf16x8 aW = *(const bf16x8*)(PWpk + (((size_t)(kb * 8 + nt) * 64 + l) << 3));
            acc[nt] = __builtin_amdgcn_mfma_f32_16x16x32_bf16(aW, b, acc[nt], 0, 0, 0);
        }
    }
    const unsigned short* arow = aggb + (size_t)n * 1536 + q * 8;
    #pragma unroll 4
    for (int kb = 4; kb < 52; ++kb) {
        bf16x8 b = {};
        if (ok) b = *(const bf16x8*)(arow + (size_t)(kb - 4) * 32);
        #pragma unroll
        for (int nt = 0; nt < 8; ++nt) {
            const bf16x8 aW = *(const bf16x8*)(PWpk + (((size_t)(kb * 8 + nt) * 64 + l) << 3));
            acc[nt] = __builtin_amdgcn_mfma_f32_16x16x32_bf16(aW, b, acc[nt], 0, 0, 0);
        }
    }
    #pragma unroll
    for (int nt = 0; nt < 8; ++nt) {
        const int col = nt * 16 + q * 4;
        const float4 bv = *(const float4*)(pb + col);
        float4 o;
        o.x = acc[nt][0] + bv.x; o.y = acc[nt][1] + bv.y;
        o.z = acc[nt][2] + bv.z; o.w = acc[nt][3] + bv.w;
        const int bcol = nt * 32 + q * 8;
        const int slot = bcol >> 4;
        const int ba = el * 256 + ((slot ^ (el & 7)) << 4) + (bcol & 15);
        *(bf16x4*)((char*)s_o16 + ba) = pack4(o);
    }
    __syncthreads();
    f32x4 acc2[8] = {};
    #pragma unroll
    for (int kb = 0; kb < 4; ++kb) {
        const int slot = kb * 4 + q;
        const int ba = el * 256 + ((slot ^ (el & 7)) << 4);
        const bf16x8 bh = *(const bf16x8*)((const char*)s_o16 + ba);
        #pragma unroll
        for (int nt = 0; nt < 8; ++nt) {
            const bf16x8 aW = *(const bf16x8*)(LNpk + (((size_t)(kb * 8 + nt) * 64 + l) << 3));
            acc2[nt] = __builtin_amdgcn_mfma_f32_16x16x32_bf16(aW, bh, acc2[nt], 0, 0, 0);
        }
    }
    if (ok) {
        float* pc = outb + (size_t)n * HD + q * 4;
        #pragma unroll
        for (int nt = 0; nt < 8; ++nt) {
            const int col = nt * 16 + q * 4;
            const float4 bv = *(const float4*)(lb + col);
            float4 o;
            o.x = acc2[nt][0] + bv.x; o.y = acc2[nt][1] + bv.y;
            o.z = acc2[nt][2] + bv.z; o.w = acc2[nt][3] + bv.w;
            *(float4*)(pc + nt * 16) = o;
        }
    }
}

// ---- BN column sums ----
__global__ void __launch_bounds__(256) k_bnstats(const float* __restrict__ ob,
        float* __restrict__ bs, float* __restrict__ bq, int M)
{
    const int c = threadIdx.x & 127;
    const int gsub = threadIdx.x >> 7;
    float s = 0.f, qq = 0.f;
    for (int rr = blockIdx.x * 2 + gsub; rr < M; rr += gridDim.x * 2) {
        const float v = ob[(size_t)rr * HD + c];
        s += v; qq += v * v;
    }
    __shared__ float ls[2][HD], lq[2][HD];
    ls[gsub][c] = s; lq[gsub][c] = qq;
    __syncthreads();
    if (gsub == 0) {
        unsafeAtomicAdd(&bs[c], ls[0][c] + ls[1][c]);
        unsafeAtomicAdd(&bq[c], lq[0][c] + lq[1][c]);
    }
}

// ---- x = (x + relu(bn(out)))/2 ----
__global__ void __launch_bounds__(256) k_xupdate(float* x, const float* __restrict__ ob,
        const float* __restrict__ bs, const float* __restrict__ bq,
        const float* __restrict__ g, const float* __restrict__ bb)
{
    const int i = blockIdx.x * 256 + threadIdx.x;
    const int c0 = (i & 31) * 4;
    const float4 ov = ((const float4*)ob)[i];
    const float4 xv = ((const float4*)x)[i];
    const float o[4]  = {ov.x, ov.y, ov.z, ov.w};
    const float xo[4] = {xv.x, xv.y, xv.z, xv.w};
    float res[4];
    #pragma unroll
    for (int j = 0; j < 4; ++j) {
        const int c = c0 + j;
        const float mu  = bs[c] * (1.f / (float)NN);
        const float var = bq[c] * (1.f / (float)NN) - mu * mu;
        const float bn  = g[c] * (o[j] - mu) * rsqrtf(var + 1e-5f) + bb[c];
        res[j] = (xo[j] + fmaxf(bn, 0.f)) * 0.5f;
    }
    ((float4*)x)[i] = make_float4(res[0], res[1], res[2], res[3]);
}

// ---- layer-0 edge update (folded): reads eatr (K=32); writes bf16 ea1 to eab ----
__global__ void __launch_bounds__(256) k_edge_upd0_T(const float* __restrict__ eatr,
        unsigned short* __restrict__ eab,
        const unsigned short* __restrict__ edgepk, const float* __restrict__ edgeb,
        const unsigned short* __restrict__ Wf1pk, const float* __restrict__ bf1,
        const unsigned short* __restrict__ e2pk, const float* __restrict__ e2b,
        const unsigned short* __restrict__ xs1b, const unsigned short* __restrict__ xd1b,
        const int* __restrict__ srcp, const int* __restrict__ dstp)
{
    __shared__ unsigned short s_hid[64 * 128];
    __shared__ float s_b2[128];
    const int t = threadIdx.x, w = t >> 6, l = t & 63;
    if (t < 128) s_b2[t] = e2b[t];
    const int el = w * 16 + (l & 15);
    const int e = blockIdx.x * 64 + el;
    const int q = l >> 4;
    const int sn = srcp[e], dn = dstp[e];
    const bf16x8 bet = load_a8(eatr + (size_t)e * EDIM + q * 8, true);
    f32x4 ea0[8] = {}, hp[8] = {};
    #pragma unroll
    for (int nt = 0; nt < 8; ++nt) {
        const bf16x8 aE = *(const bf16x8*)(edgepk + (((size_t)nt * 64 + l) << 3));
        const bf16x8 aF = *(const bf16x8*)(Wf1pk + (((size_t)nt * 64 + l) << 3));
        ea0[nt] = __builtin_amdgcn_mfma_f32_16x16x32_bf16(aE, bet, ea0[nt], 0, 0, 0);
        hp[nt]  = __builtin_amdgcn_mfma_f32_16x16x32_bf16(aF, bet, hp[nt], 0, 0, 0);
    }
    {
        const unsigned short* ps = xs1b + (size_t)sn * HD + q * 32;
        const unsigned short* pd = xd1b + (size_t)dn * HD + q * 32;
        #pragma unroll
        for (int k = 0; k < 4; ++k) {
            const int ntA = 2 * k, ntB = 2 * k + 1;
            const uint4 su = *(const uint4*)(ps + k * 8);
            const uint4 du = *(const uint4*)(pd + k * 8);
            const float4 bA = *(const float4*)(bf1 + ntA * 16 + q * 4);
            const float4 bB = *(const float4*)(bf1 + ntB * 16 + q * 4);
            float4 hA, hB;
            hA.x = fmaxf(hp[ntA][0] + bA.x + bflo2f(su.x) + bflo2f(du.x), 0.f);
            hA.y = fmaxf(hp[ntA][1] + bA.y + bfhi2f(su.x) + bfhi2f(du.x), 0.f);
            hA.z = fmaxf(hp[ntA][2] + bA.z + bflo2f(su.y) + bflo2f(du.y), 0.f);
            hA.w = fmaxf(hp[ntA][3] + bA.w + bfhi2f(su.y) + bfhi2f(du.y), 0.f);
            hB.x = fmaxf(hp[ntB][0] + bB.x + bflo2f(su.z) + bflo2f(du.z), 0.f);
            hB.y = fmaxf(hp[ntB][1] + bB.y + bfhi2f(su.z) + bfhi2f(du.z), 0.f);
            hB.z = fmaxf(hp[ntB][2] + bB.z + bflo2f(su.w) + bflo2f(du.w), 0.f);
            hB.w = fmaxf(hp[ntB][3] + bB.w + bfhi2f(su.w) + bfhi2f(du.w), 0.f);
            const int bcolA = ntA * 32 + q * 8;
            const int baA = el * 256 + (((bcolA >> 4) ^ (el & 7)) << 4) + (bcolA & 15);
            *(bf16x4*)((char*)s_hid + baA) = pack4(hA);
            const int bcolB = ntB * 32 + q * 8;
            const int baB = el * 256 + (((bcolB >> 4) ^ (el & 7)) << 4) + (bcolB & 15);
            *(bf16x4*)((char*)s_hid + baB) = pack4(hB);
        }
    }
    __syncthreads();
    f32x4 acc2[8] = {};
    #pragma unroll
    for (int kb = 0; kb < 4; ++kb) {
        const int slot = kb * 4 + q;
        const int ba = el * 256 + ((slot ^ (el & 7)) << 4);
        const bf16x8 bh = *(const bf16x8*)((const char*)s_hid + ba);
        #pragma unroll
        for (int nt = 0; nt < 8; ++nt) {
            const bf16x8 aW = *(const bf16x8*)(e2pk + (((size_t)(kb * 8 + nt) * 64 + l) << 3));
            acc2[nt] = __builtin_amdgcn_mfma_f32_16x16x32_bf16(aW, bh, acc2[nt], 0, 0, 0);
        }
    }
    // ea1 = (ea0 + edgeb) + (acc2 + e2b)/2 -> bf16 store
    {
        unsigned short* pe = eab + (size_t)e * HD + q * 4;
        #pragma unroll
        for (int nt = 0; nt < 8; ++nt) {
            const int col = nt * 16 + q * 4;
            const float4 eb = *(const float4*)(edgeb + col);
            const float4 bv = *(const float4*)(&s_b2[col]);
            float4 o;
            o.x = ea0[nt][0] + eb.x + (acc2[nt][0] + bv.x) * 0.5f;
            o.y = ea0[nt][1] + eb.y + (acc2[nt][1] + bv.y) * 0.5f;
            o.z = ea0[nt][2] + eb.z + (acc2[nt][2] + bv.z) * 0.5f;
            o.w = ea0[nt][3] + eb.w + (acc2[nt][3] + bv.w) * 0.5f;
            *(bf16x4*)(pe + nt * 16) = pack4(o);
        }
    }
}

// ---- layer-1 edge update: bf16 ea1 in, fp32 ea2 out (final output) ----
__global__ void __launch_bounds__(256) k_edge_upd_Tb(const unsigned short* __restrict__ eab,
        float* __restrict__ ea_out,
        const unsigned short* __restrict__ W1epk, const unsigned short* __restrict__ e2pk,
        const float* __restrict__ e2b, const unsigned short* __restrict__ xs1b,
        const unsigned short* __restrict__ xd1b, const int* __restrict__ srcp,
        const int* __restrict__ dstp)
{
    __shared__ unsigned short s_hid[64 * 128];
    __shared__ float s_b2[128];
    const int t = threadIdx.x, w = t >> 6, l = t & 63;
    const int row0b = blockIdx.x * 64;
    if (t < 128) s_b2[t] = e2b[t];
    const int el = w * 16 + (l & 15);
    const int e = row0b + el;
    const int q = l >> 4;
    f32x4 acc1[8] = {};
    #pragma unroll
    for (int kb = 0; kb < 4; ++kb) {
        const bf16x8 bea = *(const bf16x8*)(eab + (size_t)e * HD + kb * 32 + q * 8);
        #pragma unroll
        for (int nt = 0; nt < 8; ++nt) {
            const bf16x8 aW = *(const bf16x8*)(W1epk + (((size_t)(kb * 8 + nt) * 64 + l) << 3));
            acc1[nt] = __builtin_amdgcn_mfma_f32_16x16x32_bf16(aW, bea, acc1[nt], 0, 0, 0);
        }
    }
    {
        const int sn = srcp[e], dn = dstp[e];
        const unsigned short* ps = xs1b + (size_t)sn * HD + q * 32;
        const unsigned short* pd = xd1b + (size_t)dn * HD + q * 32;
        #pragma unroll
        for (int k = 0; k < 4; ++k) {
            const int ntA = 2 * k, ntB = 2 * k + 1;
            const uint4 su = *(const uint4*)(ps + k * 8);
            const uint4 du = *(const uint4*)(pd + k * 8);
            float4 hA, hB;
            hA.x = fmaxf(acc1[ntA][0] + bflo2f(su.x) + bflo2f(du.x), 0.f);
            hA.y = fmaxf(acc1[ntA][1] + bfhi2f(su.x) + bfhi2f(du.x), 0.f);
            hA.z = fmaxf(acc1[ntA][2] + bflo2f(su.y) + bflo2f(du.y), 0.f);
            hA.w = fmaxf(acc1[ntA][3] + bfhi2f(su.y) + bfhi2f(du.y), 0.f);
            hB.x = fmaxf(acc1[ntB][0] + bflo2f(su.z) + bflo2f(du.z), 0.f);
            hB.y = fmaxf(acc1[ntB][1] + bfhi2f(su.z) + bfhi2f(du.z), 0.f);
            hB.z = fmaxf(acc1[ntB][2] + bflo2f(su.w) + bflo2f(du.w), 0.f);
            hB.w = fmaxf(acc1[ntB][3] + bfhi2f(su.w) + bfhi2f(du.w), 0.f);
            const int bcolA = ntA * 32 + q * 8;
            const int baA = el * 256 + (((bcolA >> 4) ^ (el & 7)) << 4) + (bcolA & 15);
            *(bf16x4*)((char*)s_hid + baA) = pack4(hA);
            const int bcolB = ntB * 32 + q * 8;
            const int baB = el * 256 + (((bcolB >> 4) ^ (el & 7)) << 4) + (bcolB & 15);
            *(bf16x4*)((char*)s_hid + baB) = pack4(hB);
        }
    }
    __syncthreads();
    f32x4 acc2[8] = {};
    #pragma unroll
    for (int kb = 0; kb < 4; ++kb) {
        const int slot = kb * 4 + q;
        const int ba = el * 256 + ((slot ^ (el & 7)) << 4);
        const bf16x8 bh = *(const bf16x8*)((const char*)s_hid + ba);
        #pragma unroll
        for (int nt = 0; nt < 8; ++nt) {
            const bf16x8 aW = *(const bf16x8*)(e2pk + (((size_t)(kb * 8 + nt) * 64 + l) << 3));
            acc2[nt] = __builtin_amdgcn_mfma_f32_16x16x32_bf16(aW, bh, acc2[nt], 0, 0, 0);
        }
    }
    // ea2 = bf16(ea1) + (acc2 + e2b)/2; base re-read from bf16 (L2-hot), fp32 out
    {
        const unsigned short* pb16 = eab + (size_t)e * HD + q * 4;
        float* pe = ea_out + (size_t)e * HD + q * 4;
        #pragma unroll
        for (int nt = 0; nt < 8; ++nt) {
            const uint2 bu = *(const uint2*)(pb16 + nt * 16);
            const float4 bv = *(const float4*)(&s_b2[nt * 16 + q * 4]);
            float4 o;
            o.x = bflo2f(bu.x) + (acc2[nt][0] + bv.x) * 0.5f;
            o.y = bfhi2f(bu.x) + (acc2[nt][1] + bv.y) * 0.5f;
            o.z = bflo2f(bu.y) + (acc2[nt][2] + bv.z) * 0.5f;
            o.w = bfhi2f(bu.y) + (acc2[nt][3] + bv.w) * 0.5f;
            *(float4*)(pe + nt * 16) = o;
        }
    }
}

extern "C" void kernel_launch(void* const* d_in, const int* in_sizes, int n_in,
                              void* d_out, int out_size, void* d_ws, size_t ws_size,
                              hipStream_t stream)
{
    const float* x0    = (const float*)d_in[0];
    const float* eatr  = (const float*)d_in[1];
    const float* teatr = (const float*)d_in[2];
    const float* nodeW = (const float*)d_in[3];
    const float* nodeb = (const float*)d_in[4];
    const float* edgeW = (const float*)d_in[5];
    const float* edgeb = (const float*)d_in[6];
    const float* preW  = (const float*)d_in[7];
    const float* preb  = (const float*)d_in[8];
    const float* postW = (const float*)d_in[9];
    const float* postb = (const float*)d_in[10];
    const float* linW  = (const float*)d_in[11];
    const float* linb  = (const float*)d_in[12];
    const float* bng   = (const float*)d_in[13];
    const float* bnb   = (const float*)d_in[14];
    const float* em1W  = (const float*)d_in[15];
    const float* em1b  = (const float*)d_in[16];
    const float* em2W  = (const float*)d_in[17];
    const float* em2b  = (const float*)d_in[18];
    const int*   eidx  = (const int*)d_in[19];
    const int* srcp = eidx;
    const int* dstp = eidx + NE;

    float* out_x  = (float*)d_out;
    float* out_ea = out_x + (size_t)NN * HD;
    float* out_te = out_ea + (size_t)NE * HD;

    const size_t NH = (size_t)NN * HD;
    const size_t EH = (size_t)NE * HD;
    unsigned short* xdb = (unsigned short*)d_ws;     // fragment-major bf16 tables
    unsigned short* xsb = xdb + NH;
    unsigned short* eab = xsb + NH;                  // [NE][128] bf16 intermediate ea1
    float* outb  = (float*)(eab + EH);
    float* stats = outb + NH;
    float* Wf0   = stats + 512;        // folded edgeW@We0
    float* bf0   = Wf0 + 4096;
    float* Wf1   = bf0 + 128;          // folded edgeW@W1e0
    float* bf1   = Wf1 + 4096;
    int*   cnt      = (int*)(bf1 + 128);
    int*   row_start = cnt + NN;
    int*   cursor   = row_start + NN + 1;
    int*   tmpincl  = cursor + NN;
    int*   part     = tmpincl + NN;
    int*   poff     = part + 256;
    int*   sppos    = poff + 256;
    unsigned short* mbuf = (unsigned short*)(((uintptr_t)(sppos + NE) + 15) & ~(uintptr_t)15);
    unsigned short* aggb = mbuf + EH;
    unsigned short* pk   = aggb + (size_t)NN * 1536;
    const size_t KBSZ = 512 * 8;
    unsigned short* pkPost = pk;                       // 104 kbs
    unsigned short* pkPre  = pkPost + 104 * KBSZ;      // 24 kbs
    unsigned short* pkEm1  = pkPre  + 24 * KBSZ;       // 24 kbs
    unsigned short* pkLin  = pkEm1  + 24 * KBSZ;       // 8 kbs
    unsigned short* pkEm2  = pkLin  + 8 * KBSZ;        // 8 kbs
    unsigned short* pkNode = pkEm2  + 8 * KBSZ;        // 2 kbs
    unsigned short* pkEdge = pkNode + 2 * KBSZ;        // 1 kb
    unsigned short* pkWe0f = pkEdge + 1 * KBSZ;        // 1 kb
    unsigned short* pkWf1  = pkWe0f + 1 * KBSZ;        // 1 kb

    hipMemsetAsync(cnt, 0, NN * sizeof(int), stream);
    hipMemsetAsync(stats, 0, 512 * sizeof(float), stream);

    k_packW<<<208, 256, 0, stream>>>(postW, pkPost, 3328);
    k_packW<<<48, 256, 0, stream>>>(preW,  pkPre,  768);
    k_packW<<<48, 256, 0, stream>>>(em1W,  pkEm1,  768);
    k_packW<<<16, 256, 0, stream>>>(linW,  pkLin,  256);
    k_packW<<<16, 256, 0, stream>>>(em2W,  pkEm2,  256);
    k_packW<<<4, 256, 0, stream>>>(nodeW, pkNode, 64);
    k_packW<<<2, 256, 0, stream>>>(edgeW, pkEdge, 32);
    k_foldW<<<17, 256, 0, stream>>>(edgeW, edgeb, preW + 256 * HD, Wf0, bf0);   // msg(0)
    k_foldW<<<17, 256, 0, stream>>>(edgeW, edgeb, em1W + 256 * HD, Wf1, bf1);   // edge_upd(0) GEMM1
    k_packW<<<2, 256, 0, stream>>>(Wf0, pkWe0f, 32);
    k_packW<<<2, 256, 0, stream>>>(Wf1, pkWf1, 32);

    // prologue: teatr + node embeds only
    k_gemm_T<1><<<(NTE + 63) / 64, 256, 0, stream>>>(teatr, pkEdge, edgeb, out_te, NTE);
    k_gemm_T<2><<<(NN + 63) / 64, 256, 0, stream>>>(x0, pkNode, nodeb, out_x, NN);

    k_count<<<(NE + 255) / 256, 256, 0, stream>>>(dstp, cnt, NE);
    k_avglog<<<256, 256, 0, stream>>>(cnt, stats);
    k_scan_block<<<SCAN_B, 256, 0, stream>>>(cnt, tmpincl, part);
    k_scan_part<<<1, 256, 0, stream>>>(part, poff, SCAN_B);
    k_scan_add<<<SCAN_B, 256, 0, stream>>>(tmpincl, cnt, poff, row_start, cursor);
    k_scatter<<<(NE + 255) / 256, 256, 0, stream>>>(dstp, cursor, sppos);

    const int gn = (NN + 63) / 64;
    const int ge = NE / 64;

    const size_t PRE = 12, EM1 = 12;
    // ---- layer 0 ----
    hipMemsetAsync(stats + 128, 0, 256 * sizeof(float), stream);
    k_gemm2_Tb<4><<<gn, 256, 0, stream>>>(out_x, pkPre + 0 * KBSZ, pkPre + 4 * KBSZ, preb, xdb, xsb, NN);
    k_msg0_T<<<ge, 256, 0, stream>>>(eatr, pkWe0f, bf0, xsb, srcp, sppos, mbuf);
    k_agg<<<(NN + 3) / 4, 256, 0, stream>>>(mbuf, row_start, xdb, stats, aggb);
    k_post_lin_T<<<gn, 256, 0, stream>>>(out_x, aggb, pkPost, postb, pkLin, linb, outb, NN);
    k_bnstats<<<256, 256, 0, stream>>>(outb, stats + 128, stats + 256, NN);
    k_xupdate<<<NN * 32 / 256, 256, 0, stream>>>(out_x, outb, stats + 128, stats + 256, bng, bnb);
    k_gemm2_Tb<4><<<gn, 256, 0, stream>>>(out_x, pkEm1 + 4 * KBSZ, pkEm1 + 0 * KBSZ, em1b, xdb, xsb, NN); // xdb=W1d(+b), xsb=W1s
    k_edge_upd0_T<<<ge, 256, 0, stream>>>(eatr, eab, pkEdge, edgeb, pkWf1, bf1,
                                          pkEm2, em2b, xsb, xdb, srcp, dstp);
    // ---- layer 1 ----
    hipMemsetAsync(stats + 128, 0, 256 * sizeof(float), stream);
    k_gemm2_Tb<4><<<gn, 256, 0, stream>>>(out_x, pkPre + (PRE + 0) * KBSZ, pkPre + (PRE + 4) * KBSZ,
                                          preb + HD, xdb, xsb, NN);
    k_msg_Tb<<<ge, 256, 0, stream>>>(eab, pkPre + (PRE + 8) * KBSZ, xsb, srcp, sppos, mbuf);
    k_agg<<<(NN + 3) / 4, 256, 0, stream>>>(mbuf, row_start, xdb, stats, aggb);
    k_post_lin_T<<<gn, 256, 0, stream>>>(out_x, aggb, pkPost + 52 * KBSZ, postb + HD,
                                         pkLin + 4 * KBSZ, linb + HD, outb, NN);
    k_bnstats<<<256, 256, 0, stream>>>(outb, stats + 128, stats + 256, NN);
    k_xupdate<<<NN * 32 / 256, 256, 0, stream>>>(out_x, outb, stats + 128, stats + 256, bng + HD, bnb + HD);
    k_gemm2_Tb<4><<<gn, 256, 0, stream>>>(out_x, pkEm1 + (EM1 + 4) * KBSZ, pkEm1 + (EM1 + 0) * KBSZ,
                                          em1b + HD, xdb, xsb, NN);
    k_edge_upd_Tb<<<ge, 256, 0, stream>>>(eab, out_ea, pkEm1 + (EM1 + 8) * KBSZ,
                                          pkEm2 + 4 * KBSZ, em2b + HD, xsb, xdb, srcp, dstp);
}